// Round 2
// baseline (297.473 us; speedup 1.0000x reference)
//
#include <hip/hip_runtime.h>
#include <hip/hip_bf16.h>
#include <math.h>

#define W_  160
#define H_  128
#define HW  20480
#define D_  48
#define C_  32
#define NV  4    // source views (views 1..4)
#define CH  8    // depths per thread in k_warp_sim
#define NCH 6    // 48/8

// ---------------- tiny transform kernel ----------------

__device__ __forceinline__ void fuse_proj(const float* pm, float* P) {
  const float* E = pm;
  const float* K = pm + 16;
  for (int r = 0; r < 3; ++r)
    for (int c = 0; c < 4; ++c)
      P[r*4+c] = K[r*4+0]*E[0*4+c] + K[r*4+1]*E[1*4+c] + K[r*4+2]*E[2*4+c];
  for (int c = 0; c < 4; ++c) P[12+c] = E[12+c];
}

__device__ void invert4(const float* m, float* invOut) {
  float inv[16];
  inv[0]  =  m[5]*m[10]*m[15] - m[5]*m[11]*m[14] - m[9]*m[6]*m[15] + m[9]*m[7]*m[14] + m[13]*m[6]*m[11] - m[13]*m[7]*m[10];
  inv[4]  = -m[4]*m[10]*m[15] + m[4]*m[11]*m[14] + m[8]*m[6]*m[15] - m[8]*m[7]*m[14] - m[12]*m[6]*m[11] + m[12]*m[7]*m[10];
  inv[8]  =  m[4]*m[9]*m[15]  - m[4]*m[11]*m[13] - m[8]*m[5]*m[15] + m[8]*m[7]*m[13] + m[12]*m[5]*m[11] - m[12]*m[7]*m[9];
  inv[12] = -m[4]*m[9]*m[14]  + m[4]*m[10]*m[13] + m[8]*m[5]*m[14] - m[8]*m[6]*m[13] - m[12]*m[5]*m[10] + m[12]*m[6]*m[9];
  inv[1]  = -m[1]*m[10]*m[15] + m[1]*m[11]*m[14] + m[9]*m[2]*m[15] - m[9]*m[3]*m[14] - m[13]*m[2]*m[11] + m[13]*m[3]*m[10];
  inv[5]  =  m[0]*m[10]*m[15] - m[0]*m[11]*m[14] - m[8]*m[2]*m[15] + m[8]*m[3]*m[14] + m[12]*m[2]*m[11] - m[12]*m[3]*m[10];
  inv[9]  = -m[0]*m[9]*m[15]  + m[0]*m[11]*m[13] + m[8]*m[1]*m[15] - m[8]*m[3]*m[13] - m[12]*m[1]*m[11] + m[12]*m[3]*m[9];
  inv[13] =  m[0]*m[9]*m[14]  - m[0]*m[10]*m[13] - m[8]*m[1]*m[14] + m[8]*m[2]*m[13] + m[12]*m[1]*m[10] - m[12]*m[2]*m[9];
  inv[2]  =  m[1]*m[6]*m[15]  - m[1]*m[7]*m[14]  - m[5]*m[2]*m[15] + m[5]*m[3]*m[14] + m[13]*m[2]*m[7]  - m[13]*m[3]*m[6];
  inv[6]  = -m[0]*m[6]*m[15]  + m[0]*m[7]*m[14]  + m[4]*m[2]*m[15] - m[4]*m[3]*m[14] - m[12]*m[2]*m[7]  + m[12]*m[3]*m[6];
  inv[10] =  m[0]*m[5]*m[15]  - m[0]*m[7]*m[13]  - m[4]*m[1]*m[15] + m[4]*m[3]*m[13] + m[12]*m[1]*m[7]  - m[12]*m[3]*m[5];
  inv[14] = -m[0]*m[5]*m[14]  + m[0]*m[6]*m[13]  + m[4]*m[1]*m[14] - m[4]*m[2]*m[13] - m[12]*m[1]*m[6]  + m[12]*m[2]*m[5];
  inv[3]  = -m[1]*m[6]*m[11]  + m[1]*m[7]*m[10]  + m[5]*m[2]*m[11] - m[5]*m[3]*m[10] - m[9]*m[2]*m[7]   + m[9]*m[3]*m[6];
  inv[7]  =  m[0]*m[6]*m[11]  - m[0]*m[7]*m[10]  - m[4]*m[2]*m[11] + m[4]*m[3]*m[10] + m[8]*m[2]*m[7]   - m[8]*m[3]*m[6];
  inv[11] = -m[0]*m[5]*m[11]  + m[0]*m[7]*m[9]   + m[4]*m[1]*m[11] - m[4]*m[3]*m[9]  - m[8]*m[1]*m[7]   + m[8]*m[3]*m[5];
  inv[15] =  m[0]*m[5]*m[10]  - m[0]*m[6]*m[9]   - m[4]*m[1]*m[10] + m[4]*m[2]*m[9]  + m[8]*m[1]*m[6]   - m[8]*m[2]*m[5];
  float det = m[0]*inv[0] + m[1]*inv[4] + m[2]*inv[8] + m[3]*inv[12];
  det = 1.0f / det;
  for (int i = 0; i < 16; i++) invOut[i] = inv[i] * det;
}

// xf layout per src view v (0..3): [r00 r01 r02 r10 r11 r12 r20 r21 r22 t0 t1 t2]
__global__ void k_xform(const float* __restrict__ pm, float* __restrict__ xf) {
  if (blockIdx.x || threadIdx.x) return;
  float Pr[16], Pinv[16], Ps[16], M[16];
  fuse_proj(pm, Pr);
  invert4(Pr, Pinv);
  for (int v = 1; v <= NV; ++v) {
    fuse_proj(pm + v*32, Ps);
    for (int r = 0; r < 4; ++r)
      for (int c = 0; c < 4; ++c) {
        float a = 0.f;
        for (int k = 0; k < 4; ++k) a += Ps[r*4+k]*Pinv[k*4+c];
        M[r*4+c] = a;
      }
    float* o = xf + (v-1)*12;
    o[0]=M[0];  o[1]=M[1];  o[2]=M[2];
    o[3]=M[4];  o[4]=M[5];  o[5]=M[6];
    o[6]=M[8];  o[7]=M[9];  o[8]=M[10];
    o[9]=M[3];  o[10]=M[7]; o[11]=M[11];
  }
}

// ---------------- transpose (V,C,H,W) -> (V,HW,C) ----------------
__global__ void k_transpose(const float* __restrict__ feat, float* __restrict__ tf) {
  int idx = blockIdx.x*blockDim.x + threadIdx.x;
  if (idx >= 5*HW) return;
  int p = idx % HW;
  int v = idx / HW;
  const float* src = feat + (size_t)v*C_*HW + p;
  float4* dst = (float4*)(tf + ((size_t)v*HW + p)*C_);
  #pragma unroll
  for (int c0 = 0; c0 < C_; c0 += 4) {
    float4 t;
    t.x = src[(size_t)(c0+0)*HW];
    t.y = src[(size_t)(c0+1)*HW];
    t.z = src[(size_t)(c0+2)*HW];
    t.w = src[(size_t)(c0+3)*HW];
    dst[c0/4] = t;
  }
}

// ---------------- main warp + similarity + MLP kernel ----------------
// All per-depth state lives in arrays indexed ONLY inside fully-unrolled
// loops (static indices -> registers, no scratch). Addresses/weights for all
// CH depths are computed before any gather, so the compiler can keep several
// depths' loads in flight under the __launch_bounds__ register cap.
__global__ void __launch_bounds__(256, 3)
k_warp_sim(const float* __restrict__ tf, const float* __restrict__ dv,
           const float* __restrict__ xf,
           const float* __restrict__ w0, const float* __restrict__ b0,
           const float* __restrict__ w1, const float* __restrict__ b1,
           const float* __restrict__ w2, const float* __restrict__ b2,
           float* __restrict__ sim_all, float* __restrict__ yp) {
  int idx = blockIdx.x*blockDim.x + threadIdx.x;   // (chunk, v, p), p fastest
  if (idx >= NV*NCH*HW) return;
  int p = idx % HW;
  int t = idx / HW;
  int v = t & 3;
  int chunk = t >> 2;

  float xpix = (float)(p % W_);
  float ypix = (float)(p / W_);

  const float* M = xf + v*12;
  float rx = M[0]*xpix + M[1]*ypix + M[2];
  float ry = M[3]*xpix + M[4]*ypix + M[5];
  float rz = M[6]*xpix + M[7]*ypix + M[8];
  float t0 = M[9], t1 = M[10], t2 = M[11];

  // depth values for this chunk (coalesced, issued up front)
  float dep[CH];
  #pragma unroll
  for (int dd = 0; dd < CH; ++dd)
    dep[dd] = dv[(size_t)(chunk*CH + dd)*HW + p];

  // ref feature vector (view 0)
  float rf[C_];
  {
    const float4* rq = (const float4*)(tf + (size_t)p*C_);
    #pragma unroll
    for (int c4 = 0; c4 < C_/4; ++c4) {
      float4 q = rq[c4];
      rf[c4*4+0]=q.x; rf[c4*4+1]=q.y; rf[c4*4+2]=q.z; rf[c4*4+3]=q.w;
    }
  }
  const float* srcb = tf + (size_t)(v+1)*HW*C_;

  // project all depths: px,py
  float pxv[CH], pyv[CH];
  #pragma unroll
  for (int dd = 0; dd < CH; ++dd) {
    float X = rx*dep[dd] + t0;
    float Y = ry*dep[dd] + t1;
    float Z = rz*dep[dd] + t2;
    pxv[dd] = X / Z;
    pyv[dd] = Y / Z;
  }

  // addresses (element offsets) + bilinear weights for all depths
  int   o00[CH], o01[CH], o10[CH], o11[CH];
  float w00[CH], w01[CH], w10[CH], w11[CH];
  #pragma unroll
  for (int dd = 0; dd < CH; ++dd) {
    float px = pxv[dd], py = pyv[dd];
    float x0f = floorf(px), y0f = floorf(py);
    float x1f = x0f + 1.0f, y1f = y0f + 1.0f;
    float wx1 = px - x0f, wx0 = 1.0f - wx1;
    float wy1 = py - y0f, wy0 = 1.0f - wy1;
    bool vx0 = (x0f >= 0.0f) && (x0f <= (float)(W_-1));
    bool vx1 = (x1f >= 0.0f) && (x1f <= (float)(W_-1));
    bool vy0 = (y0f >= 0.0f) && (y0f <= (float)(H_-1));
    bool vy1 = (y1f >= 0.0f) && (y1f <= (float)(H_-1));
    int cx0 = (int)fminf(fmaxf(x0f, 0.0f), (float)(W_-1));
    int cx1 = (int)fminf(fmaxf(x1f, 0.0f), (float)(W_-1));
    int cy0 = (int)fminf(fmaxf(y0f, 0.0f), (float)(H_-1));
    int cy1 = (int)fminf(fmaxf(y1f, 0.0f), (float)(H_-1));
    w00[dd] = wx0*wy0*((vx0&&vy0)?1.f:0.f);
    w01[dd] = wx1*wy0*((vx1&&vy0)?1.f:0.f);
    w10[dd] = wx0*wy1*((vx0&&vy1)?1.f:0.f);
    w11[dd] = wx1*wy1*((vx1&&vy1)?1.f:0.f);
    o00[dd] = (cy0*W_+cx0)*C_;
    o01[dd] = (cy0*W_+cx1)*C_;
    o10[dd] = (cy1*W_+cx0)*C_;
    o11[dd] = (cy1*W_+cx1)*C_;
  }

  // gathers + dots + MLP, fully unrolled so the scheduler can pipeline
  float ymax = -3.0e38f;
  #pragma unroll
  for (int dd = 0; dd < CH; ++dd) {
    const float4* q00 = (const float4*)(srcb + o00[dd]);
    const float4* q01 = (const float4*)(srcb + o01[dd]);
    const float4* q10 = (const float4*)(srcb + o10[dd]);
    const float4* q11 = (const float4*)(srcb + o11[dd]);

    float d00=0.f, d01=0.f, d10=0.f, d11=0.f;
    #pragma unroll
    for (int c4 = 0; c4 < C_/4; ++c4) {
      float4 a = q00[c4], b = q01[c4], g = q10[c4], e = q11[c4];
      d00 += a.x*rf[c4*4+0] + a.y*rf[c4*4+1] + a.z*rf[c4*4+2] + a.w*rf[c4*4+3];
      d01 += b.x*rf[c4*4+0] + b.y*rf[c4*4+1] + b.z*rf[c4*4+2] + b.w*rf[c4*4+3];
      d10 += g.x*rf[c4*4+0] + g.y*rf[c4*4+1] + g.z*rf[c4*4+2] + g.w*rf[c4*4+3];
      d11 += e.x*rf[c4*4+0] + e.y*rf[c4*4+1] + e.z*rf[c4*4+2] + e.w*rf[c4*4+3];
    }
    float sim = (w00[dd]*d00 + w01[dd]*d01 + w10[dd]*d10 + w11[dd]*d11) * (1.0f/(float)C_);

    sim_all[(size_t)(v*D_ + chunk*CH + dd)*HW + p] = sim;

    // MLP: 1 -> 16 -> 8 -> 1 (independent per depth; overlaps later gathers)
    float h0[16];
    #pragma unroll
    for (int o = 0; o < 16; ++o) h0[o] = fmaxf(w0[o]*sim + b0[o], 0.0f);
    float yv = b2[0];
    #pragma unroll
    for (int j = 0; j < 8; ++j) {
      float a = b1[j];
      #pragma unroll
      for (int o = 0; o < 16; ++o) a += w1[j*16+o]*h0[o];
      yv += w2[j]*fmaxf(a, 0.0f);
    }
    ymax = fmaxf(ymax, yv);
  }
  yp[(size_t)(v*NCH + chunk)*HW + p] = ymax;
}

// ---------------- view weight: sigmoid(max over chunks) ----------------
__global__ void k_vw(const float* __restrict__ yp, float* __restrict__ vw,
                     float* __restrict__ out) {
  int idx = blockIdx.x*blockDim.x + threadIdx.x;   // (v,p)
  if (idx >= NV*HW) return;
  int p = idx % HW;
  int v = idx / HW;
  float m = yp[(size_t)(v*NCH+0)*HW + p];
  #pragma unroll
  for (int c = 1; c < NCH; ++c)
    m = fmaxf(m, yp[(size_t)(v*NCH+c)*HW + p]);
  float s = 1.0f / (1.0f + expf(-m));
  vw[(size_t)v*HW + p] = s;
  out[(size_t)(2*HW + D_*HW) + (size_t)v*HW + p] = s;
}

// ---------------- fuse views ----------------
__global__ void k_fuse(const float* __restrict__ sim_all, const float* __restrict__ vw,
                       float* __restrict__ fus) {
  int idx = blockIdx.x*blockDim.x + threadIdx.x;   // (d,p)
  if (idx >= D_*HW) return;
  int p = idx % HW;
  int d = idx / HW;
  float wsum = 1e-5f;
  float ssum = 0.0f;
  #pragma unroll
  for (int v = 0; v < NV; ++v) {
    float s = sim_all[(size_t)(v*D_ + d)*HW + p];
    float w = vw[(size_t)v*HW + p];
    ssum += s*w;
    wsum += w;
  }
  fus[(size_t)d*HW + p] = ssum / wsum;
}

// ---------------- 3x3x3 conv (cross-correlation, zero pad SAME) ----------------
__global__ void k_conv(const float* __restrict__ fus, const float* __restrict__ rw,
                       const float* __restrict__ rb, float* __restrict__ cost) {
  int idx = blockIdx.x*blockDim.x + threadIdx.x;   // (d,p)
  if (idx >= D_*HW) return;
  int p = idx % HW;
  int d = idx / HW;
  int x = p % W_;
  int y = p / W_;
  float acc = rb[0];
  #pragma unroll
  for (int kd = 0; kd < 3; ++kd) {
    int dz = d + kd - 1;
    if (dz < 0 || dz >= D_) continue;
    #pragma unroll
    for (int kh = 0; kh < 3; ++kh) {
      int yy = y + kh - 1;
      if (yy < 0 || yy >= H_) continue;
      #pragma unroll
      for (int kw = 0; kw < 3; ++kw) {
        int xx = x + kw - 1;
        if (xx < 0 || xx >= W_) continue;
        acc += fus[(size_t)dz*HW + yy*W_ + xx] * rw[(kd*3+kh)*3+kw];
      }
    }
  }
  cost[(size_t)d*HW + p] = acc;
}

// ---------------- softmax / argmax / outputs ----------------
__global__ void k_softmax(const float* __restrict__ cost, const float* __restrict__ dv,
                          float* __restrict__ out) {
  int p = blockIdx.x*blockDim.x + threadIdx.x;
  if (p >= HW) return;
  float vbuf[D_];
  #pragma unroll
  for (int d = 0; d < D_; ++d) vbuf[d] = cost[(size_t)d*HW + p];
  float vmax = vbuf[0];
  int am = 0;
  #pragma unroll
  for (int d = 1; d < D_; ++d) {
    if (vbuf[d] > vmax) { vmax = vbuf[d]; am = d; }
  }
  float sum = 0.0f;
  #pragma unroll
  for (int d = 0; d < D_; ++d) {
    float e = expf(vbuf[d] - vmax);
    vbuf[d] = e;
    sum += e;
  }
  float inv = 1.0f / sum;
  #pragma unroll
  for (int d = 0; d < D_; ++d) {
    out[(size_t)(2*HW) + (size_t)d*HW + p] = vbuf[d] * inv;   // prob
  }
  out[p] = dv[(size_t)am*HW + p];   // depth at argmax
  out[HW + p] = inv;                // conf = max prob = exp(0)/sum
}

// ---------------- launch ----------------
extern "C" void kernel_launch(void* const* d_in, const int* in_sizes, int n_in,
                              void* d_out, int out_size, void* d_ws, size_t ws_size,
                              hipStream_t stream) {
  const float* feat = (const float*)d_in[0];
  const float* pm   = (const float*)d_in[1];
  const float* dv   = (const float*)d_in[2];
  const float* w0   = (const float*)d_in[3];
  const float* b0   = (const float*)d_in[4];
  const float* w1   = (const float*)d_in[5];
  const float* b1   = (const float*)d_in[6];
  const float* w2   = (const float*)d_in[7];
  const float* b2   = (const float*)d_in[8];
  const float* rw   = (const float*)d_in[9];
  const float* rb   = (const float*)d_in[10];
  float* out = (float*)d_out;
  float* ws  = (float*)d_ws;

  // workspace layout (floats)
  float* xf   = ws;                  // 48 (pad 64)
  float* tf   = ws + 64;             // 5*HW*C = 3,276,800 floats
  float* sim  = ws + 3276864;        // 4*48*HW = 3,932,160
  float* yp   = ws + 7209024;        // 4*6*HW = 491,520
  float* vw   = ws + 7700544;        // 4*HW = 81,920
  // tf is dead after k_warp_sim: overlay fus and cost on it
  float* fus  = ws + 64;             // 48*HW = 983,040
  float* cost = ws + 64 + 983040;    // 48*HW = 983,040
  // high-water mark: 7,782,464 floats = ~29.7 MB

  hipLaunchKernelGGL(k_xform, dim3(1), dim3(64), 0, stream, pm, xf);
  hipLaunchKernelGGL(k_transpose, dim3((5*HW)/256), dim3(256), 0, stream, feat, tf);
  hipLaunchKernelGGL(k_warp_sim, dim3((NV*NCH*HW)/256), dim3(256), 0, stream,
                     tf, dv, xf, w0, b0, w1, b1, w2, b2, sim, yp);
  hipLaunchKernelGGL(k_vw, dim3((NV*HW)/256), dim3(256), 0, stream, yp, vw, out);
  hipLaunchKernelGGL(k_fuse, dim3((D_*HW)/256), dim3(256), 0, stream, sim, vw, fus);
  hipLaunchKernelGGL(k_conv, dim3((D_*HW)/256), dim3(256), 0, stream, fus, rw, rb, cost);
  hipLaunchKernelGGL(k_softmax, dim3(HW/256), dim3(256), 0, stream, cost, dv, out);
}

// Round 3
// 161.232 us; speedup vs baseline: 1.8450x; 1.8450x over previous
//
#include <hip/hip_runtime.h>
#include <hip/hip_bf16.h>
#include <math.h>

#define W_  160
#define H_  128
#define HW  20480
#define D_  48
#define C_  32
#define NV  4    // source views (views 1..4)
#define CH  12   // depths per thread in k_mlp
#define NCH 4    // 48/12

// ---------------- tiny transform kernel ----------------

__device__ __forceinline__ void fuse_proj(const float* pm, float* P) {
  const float* E = pm;
  const float* K = pm + 16;
  for (int r = 0; r < 3; ++r)
    for (int c = 0; c < 4; ++c)
      P[r*4+c] = K[r*4+0]*E[0*4+c] + K[r*4+1]*E[1*4+c] + K[r*4+2]*E[2*4+c];
  for (int c = 0; c < 4; ++c) P[12+c] = E[12+c];
}

__device__ void invert4(const float* m, float* invOut) {
  float inv[16];
  inv[0]  =  m[5]*m[10]*m[15] - m[5]*m[11]*m[14] - m[9]*m[6]*m[15] + m[9]*m[7]*m[14] + m[13]*m[6]*m[11] - m[13]*m[7]*m[10];
  inv[4]  = -m[4]*m[10]*m[15] + m[4]*m[11]*m[14] + m[8]*m[6]*m[15] - m[8]*m[7]*m[14] - m[12]*m[6]*m[11] + m[12]*m[7]*m[10];
  inv[8]  =  m[4]*m[9]*m[15]  - m[4]*m[11]*m[13] - m[8]*m[5]*m[15] + m[8]*m[7]*m[13] + m[12]*m[5]*m[11] - m[12]*m[7]*m[9];
  inv[12] = -m[4]*m[9]*m[14]  + m[4]*m[10]*m[13] + m[8]*m[5]*m[14] - m[8]*m[6]*m[13] - m[12]*m[5]*m[10] + m[12]*m[6]*m[9];
  inv[1]  = -m[1]*m[10]*m[15] + m[1]*m[11]*m[14] + m[9]*m[2]*m[15] - m[9]*m[3]*m[14] - m[13]*m[2]*m[11] + m[13]*m[3]*m[10];
  inv[5]  =  m[0]*m[10]*m[15] - m[0]*m[11]*m[14] - m[8]*m[2]*m[15] + m[8]*m[3]*m[14] + m[12]*m[2]*m[11] - m[12]*m[3]*m[10];
  inv[9]  = -m[0]*m[9]*m[15]  + m[0]*m[11]*m[13] + m[8]*m[1]*m[15] - m[8]*m[3]*m[13] - m[12]*m[1]*m[11] + m[12]*m[3]*m[9];
  inv[13] =  m[0]*m[9]*m[14]  - m[0]*m[10]*m[13] - m[8]*m[1]*m[14] + m[8]*m[2]*m[13] + m[12]*m[1]*m[10] - m[12]*m[2]*m[9];
  inv[2]  =  m[1]*m[6]*m[15]  - m[1]*m[7]*m[14]  - m[5]*m[2]*m[15] + m[5]*m[3]*m[14] + m[13]*m[2]*m[7]  - m[13]*m[3]*m[6];
  inv[6]  = -m[0]*m[6]*m[15]  + m[0]*m[7]*m[14]  + m[4]*m[2]*m[15] - m[4]*m[3]*m[14] - m[12]*m[2]*m[7]  + m[12]*m[3]*m[6];
  inv[10] =  m[0]*m[5]*m[15]  - m[0]*m[7]*m[13]  - m[4]*m[1]*m[15] + m[4]*m[3]*m[13] + m[12]*m[1]*m[7]  - m[12]*m[3]*m[5];
  inv[14] = -m[0]*m[5]*m[14]  + m[0]*m[6]*m[13]  + m[4]*m[1]*m[14] - m[4]*m[2]*m[13] - m[12]*m[1]*m[6]  + m[12]*m[2]*m[5];
  inv[3]  = -m[1]*m[6]*m[11]  + m[1]*m[7]*m[10]  + m[5]*m[2]*m[11] - m[5]*m[3]*m[10] - m[9]*m[2]*m[7]   + m[9]*m[3]*m[6];
  inv[7]  =  m[0]*m[6]*m[11]  - m[0]*m[7]*m[10]  - m[4]*m[2]*m[11] + m[4]*m[3]*m[10] + m[8]*m[2]*m[7]   - m[8]*m[3]*m[6];
  inv[11] = -m[0]*m[5]*m[11]  + m[0]*m[7]*m[9]   + m[4]*m[1]*m[11] - m[4]*m[3]*m[9]  - m[8]*m[1]*m[7]   + m[8]*m[3]*m[5];
  inv[15] =  m[0]*m[5]*m[10]  - m[0]*m[6]*m[9]   - m[4]*m[1]*m[10] + m[4]*m[2]*m[9]  + m[8]*m[1]*m[6]   - m[8]*m[2]*m[5];
  float det = m[0]*inv[0] + m[1]*inv[4] + m[2]*inv[8] + m[3]*inv[12];
  det = 1.0f / det;
  for (int i = 0; i < 16; i++) invOut[i] = inv[i] * det;
}

// xf layout per src view v (0..3): [r00 r01 r02 r10 r11 r12 r20 r21 r22 t0 t1 t2]
__global__ void k_xform(const float* __restrict__ pm, float* __restrict__ xf) {
  if (blockIdx.x || threadIdx.x) return;
  float Pr[16], Pinv[16], Ps[16], M[16];
  fuse_proj(pm, Pr);
  invert4(Pr, Pinv);
  for (int v = 1; v <= NV; ++v) {
    fuse_proj(pm + v*32, Ps);
    for (int r = 0; r < 4; ++r)
      for (int c = 0; c < 4; ++c) {
        float a = 0.f;
        for (int k = 0; k < 4; ++k) a += Ps[r*4+k]*Pinv[k*4+c];
        M[r*4+c] = a;
      }
    float* o = xf + (v-1)*12;
    o[0]=M[0];  o[1]=M[1];  o[2]=M[2];
    o[3]=M[4];  o[4]=M[5];  o[5]=M[6];
    o[6]=M[8];  o[7]=M[9];  o[8]=M[10];
    o[9]=M[3];  o[10]=M[7]; o[11]=M[11];
  }
}

// ---------------- transpose (V,C,H,W) -> (V,HW,C) ----------------
// 8 lanes per pixel, each lane owns 4 channels -> fully coalesced 1KB stores.
__global__ void k_transpose(const float* __restrict__ feat, float* __restrict__ tf) {
  int idx = blockIdx.x*blockDim.x + threadIdx.x;   // (v, p, ch)
  if (idx >= 5*HW*8) return;
  int ch = idx & 7;
  int rest = idx >> 3;
  int p = rest % HW;
  int v = rest / HW;
  const float* src = feat + (size_t)v*C_*HW + (size_t)(ch*4)*HW + p;
  float4 t;
  t.x = src[0*HW];
  t.y = src[1*HW];
  t.z = src[2*HW];
  t.w = src[3*HW];
  *(float4*)(tf + ((size_t)v*HW + p)*C_ + ch*4) = t;
}

// ---------------- main warp + similarity kernel ----------------
// Wave = 8 pixels x 8 channel-chunks. Corner loads are one float4/lane; the
// 8 lanes of a pixel-group cover one contiguous 128B feature vector, so each
// wave load instruction touches ~8 contiguous cache lines (vs 64 scattered).
__global__ void __launch_bounds__(256)
k_warp(const float* __restrict__ tf, const float* __restrict__ dv,
       const float* __restrict__ xf, float* __restrict__ sim_all) {
  int tid = blockIdx.x*blockDim.x + threadIdx.x;
  int lane = threadIdx.x & 63;
  int ch = lane & 7;              // channel chunk (0..7)
  int wv = tid >> 6;              // global wave id: (v, pixel-group)
  const int PGPV = HW/8;          // 2560 pixel-groups per view
  int pg = wv % PGPV;
  int v  = wv / PGPV;
  int p  = pg*8 + ((lane>>3)&7);

  float xpix = (float)(p % W_);
  float ypix = (float)(p / W_);

  const float* M = xf + v*12;
  float rx = M[0]*xpix + M[1]*ypix + M[2];
  float ry = M[3]*xpix + M[4]*ypix + M[5];
  float rz = M[6]*xpix + M[7]*ypix + M[8];
  float t0 = M[9], t1 = M[10], t2 = M[11];

  // this lane's 4-channel slice of the ref feature
  float4 rfc = *(const float4*)(tf + (size_t)p*C_ + ch*4);
  const float* srcb = tf + (size_t)(v+1)*HW*C_ + ch*4;

  float* simv = sim_all + (size_t)v*D_*HW + p;

  #pragma unroll 4
  for (int d = 0; d < D_; ++d) {
    float dep = dv[(size_t)d*HW + p];
    float X = rx*dep + t0;
    float Y = ry*dep + t1;
    float Z = rz*dep + t2;
    float px = X / Z;
    float py = Y / Z;

    float x0f = floorf(px), y0f = floorf(py);
    float x1f = x0f + 1.0f, y1f = y0f + 1.0f;
    float wx1 = px - x0f, wx0 = 1.0f - wx1;
    float wy1 = py - y0f, wy0 = 1.0f - wy1;
    bool vx0 = (x0f >= 0.0f) && (x0f <= (float)(W_-1));
    bool vx1 = (x1f >= 0.0f) && (x1f <= (float)(W_-1));
    bool vy0 = (y0f >= 0.0f) && (y0f <= (float)(H_-1));
    bool vy1 = (y1f >= 0.0f) && (y1f <= (float)(H_-1));
    int cx0 = (int)fminf(fmaxf(x0f, 0.0f), (float)(W_-1));
    int cx1 = (int)fminf(fmaxf(x1f, 0.0f), (float)(W_-1));
    int cy0 = (int)fminf(fmaxf(y0f, 0.0f), (float)(H_-1));
    int cy1 = (int)fminf(fmaxf(y1f, 0.0f), (float)(H_-1));
    float w00 = wx0*wy0*((vx0&&vy0)?1.f:0.f);
    float w01 = wx1*wy0*((vx1&&vy0)?1.f:0.f);
    float w10 = wx0*wy1*((vx0&&vy1)?1.f:0.f);
    float w11 = wx1*wy1*((vx1&&vy1)?1.f:0.f);

    float4 a = *(const float4*)(srcb + (size_t)(cy0*W_+cx0)*C_);
    float4 b = *(const float4*)(srcb + (size_t)(cy0*W_+cx1)*C_);
    float4 g = *(const float4*)(srcb + (size_t)(cy1*W_+cx0)*C_);
    float4 e = *(const float4*)(srcb + (size_t)(cy1*W_+cx1)*C_);

    float d00 = a.x*rfc.x + a.y*rfc.y + a.z*rfc.z + a.w*rfc.w;
    float d01 = b.x*rfc.x + b.y*rfc.y + b.z*rfc.z + b.w*rfc.w;
    float d10 = g.x*rfc.x + g.y*rfc.y + g.z*rfc.z + g.w*rfc.w;
    float d11 = e.x*rfc.x + e.y*rfc.y + e.z*rfc.z + e.w*rfc.w;
    float s = w00*d00 + w01*d01 + w10*d10 + w11*d11;

    // reduce across the 8 channel lanes
    s += __shfl_xor(s, 1);
    s += __shfl_xor(s, 2);
    s += __shfl_xor(s, 4);

    if (ch == 0) simv[(size_t)d*HW] = s * (1.0f/(float)C_);
  }
}

// ---------------- MLP over sim chunks: partial max of logit ----------------
__global__ void k_mlp(const float* __restrict__ sim_all,
                      const float* __restrict__ w0, const float* __restrict__ b0,
                      const float* __restrict__ w1, const float* __restrict__ b1,
                      const float* __restrict__ w2, const float* __restrict__ b2,
                      float* __restrict__ yp) {
  int idx = blockIdx.x*blockDim.x + threadIdx.x;   // (chunk, v, p), p fastest
  if (idx >= NV*NCH*HW) return;
  int p = idx % HW;
  int t = idx / HW;
  int v = t & 3;
  int chunk = t >> 2;

  float ymax = -3.0e38f;
  #pragma unroll
  for (int dd = 0; dd < CH; ++dd) {
    int d = chunk*CH + dd;
    float sim = sim_all[(size_t)(v*D_ + d)*HW + p];
    float h0[16];
    #pragma unroll
    for (int o = 0; o < 16; ++o) h0[o] = fmaxf(w0[o]*sim + b0[o], 0.0f);
    float yv = b2[0];
    #pragma unroll
    for (int j = 0; j < 8; ++j) {
      float a = b1[j];
      #pragma unroll
      for (int o = 0; o < 16; ++o) a += w1[j*16+o]*h0[o];
      yv += w2[j]*fmaxf(a, 0.0f);
    }
    ymax = fmaxf(ymax, yv);
  }
  yp[(size_t)(v*NCH + chunk)*HW + p] = ymax;
}

// ---------------- view weight: sigmoid(max over chunks) ----------------
__global__ void k_vw(const float* __restrict__ yp, float* __restrict__ vw,
                     float* __restrict__ out) {
  int idx = blockIdx.x*blockDim.x + threadIdx.x;   // (v,p)
  if (idx >= NV*HW) return;
  int p = idx % HW;
  int v = idx / HW;
  float m = yp[(size_t)(v*NCH+0)*HW + p];
  #pragma unroll
  for (int c = 1; c < NCH; ++c)
    m = fmaxf(m, yp[(size_t)(v*NCH+c)*HW + p]);
  float s = 1.0f / (1.0f + expf(-m));
  vw[(size_t)v*HW + p] = s;
  out[(size_t)(2*HW + D_*HW) + (size_t)v*HW + p] = s;
}

// ---------------- fuse views ----------------
__global__ void k_fuse(const float* __restrict__ sim_all, const float* __restrict__ vw,
                       float* __restrict__ fus) {
  int idx = blockIdx.x*blockDim.x + threadIdx.x;   // (d,p)
  if (idx >= D_*HW) return;
  int p = idx % HW;
  int d = idx / HW;
  float wsum = 1e-5f;
  float ssum = 0.0f;
  #pragma unroll
  for (int v = 0; v < NV; ++v) {
    float s = sim_all[(size_t)(v*D_ + d)*HW + p];
    float w = vw[(size_t)v*HW + p];
    ssum += s*w;
    wsum += w;
  }
  fus[(size_t)d*HW + p] = ssum / wsum;
}

// ---------------- 3x3x3 conv (cross-correlation, zero pad SAME) ----------------
__global__ void k_conv(const float* __restrict__ fus, const float* __restrict__ rw,
                       const float* __restrict__ rb, float* __restrict__ cost) {
  int idx = blockIdx.x*blockDim.x + threadIdx.x;   // (d,p)
  if (idx >= D_*HW) return;
  int p = idx % HW;
  int d = idx / HW;
  int x = p % W_;
  int y = p / W_;
  float acc = rb[0];
  #pragma unroll
  for (int kd = 0; kd < 3; ++kd) {
    int dz = d + kd - 1;
    if (dz < 0 || dz >= D_) continue;
    #pragma unroll
    for (int kh = 0; kh < 3; ++kh) {
      int yy = y + kh - 1;
      if (yy < 0 || yy >= H_) continue;
      #pragma unroll
      for (int kw = 0; kw < 3; ++kw) {
        int xx = x + kw - 1;
        if (xx < 0 || xx >= W_) continue;
        acc += fus[(size_t)dz*HW + yy*W_ + xx] * rw[(kd*3+kh)*3+kw];
      }
    }
  }
  cost[(size_t)d*HW + p] = acc;
}

// ---------------- softmax / argmax / outputs ----------------
__global__ void k_softmax(const float* __restrict__ cost, const float* __restrict__ dv,
                          float* __restrict__ out) {
  int p = blockIdx.x*blockDim.x + threadIdx.x;
  if (p >= HW) return;
  float vbuf[D_];
  #pragma unroll
  for (int d = 0; d < D_; ++d) vbuf[d] = cost[(size_t)d*HW + p];
  float vmax = vbuf[0];
  int am = 0;
  #pragma unroll
  for (int d = 1; d < D_; ++d) {
    if (vbuf[d] > vmax) { vmax = vbuf[d]; am = d; }
  }
  float sum = 0.0f;
  #pragma unroll
  for (int d = 0; d < D_; ++d) {
    float e = expf(vbuf[d] - vmax);
    vbuf[d] = e;
    sum += e;
  }
  float inv = 1.0f / sum;
  #pragma unroll
  for (int d = 0; d < D_; ++d) {
    out[(size_t)(2*HW) + (size_t)d*HW + p] = vbuf[d] * inv;   // prob
  }
  out[p] = dv[(size_t)am*HW + p];   // depth at argmax
  out[HW + p] = inv;                // conf = max prob = exp(0)/sum
}

// ---------------- launch ----------------
extern "C" void kernel_launch(void* const* d_in, const int* in_sizes, int n_in,
                              void* d_out, int out_size, void* d_ws, size_t ws_size,
                              hipStream_t stream) {
  const float* feat = (const float*)d_in[0];
  const float* pm   = (const float*)d_in[1];
  const float* dv   = (const float*)d_in[2];
  const float* w0   = (const float*)d_in[3];
  const float* b0   = (const float*)d_in[4];
  const float* w1   = (const float*)d_in[5];
  const float* b1   = (const float*)d_in[6];
  const float* w2   = (const float*)d_in[7];
  const float* b2   = (const float*)d_in[8];
  const float* rw   = (const float*)d_in[9];
  const float* rb   = (const float*)d_in[10];
  float* out = (float*)d_out;
  float* ws  = (float*)d_ws;

  // workspace layout (floats)
  float* xf   = ws;                  // 48 (pad 64)
  float* tf   = ws + 64;             // 5*HW*C = 3,276,800 floats
  float* sim  = ws + 3276864;        // 4*48*HW = 3,932,160
  float* yp   = ws + 7209024;        // 4*4*HW = 327,680
  float* vw   = ws + 7536704;        // 4*HW = 81,920
  // tf is dead after k_warp: overlay fus and cost on it
  float* fus  = ws + 64;             // 48*HW = 983,040
  float* cost = ws + 64 + 983040;    // 48*HW = 983,040
  // high-water mark: ~7.62M floats = ~29 MB

  hipLaunchKernelGGL(k_xform, dim3(1), dim3(64), 0, stream, pm, xf);
  hipLaunchKernelGGL(k_transpose, dim3((5*HW*8)/256), dim3(256), 0, stream, feat, tf);
  hipLaunchKernelGGL(k_warp, dim3((NV*HW*8)/256), dim3(256), 0, stream, tf, dv, xf, sim);
  hipLaunchKernelGGL(k_mlp, dim3((NV*NCH*HW)/256), dim3(256), 0, stream,
                     sim, w0, b0, w1, b1, w2, b2, yp);
  hipLaunchKernelGGL(k_vw, dim3((NV*HW)/256), dim3(256), 0, stream, yp, vw, out);
  hipLaunchKernelGGL(k_fuse, dim3((D_*HW)/256), dim3(256), 0, stream, sim, vw, fus);
  hipLaunchKernelGGL(k_conv, dim3((D_*HW)/256), dim3(256), 0, stream, fus, rw, rb, cost);
  hipLaunchKernelGGL(k_softmax, dim3(HW/256), dim3(256), 0, stream, cost, dv, out);
}

// Round 4
// 149.206 us; speedup vs baseline: 1.9937x; 1.0806x over previous
//
#include <hip/hip_runtime.h>
#include <hip/hip_bf16.h>
#include <math.h>

#define W_  160
#define H_  128
#define HW  20480
#define D_  48
#define C_  32
#define NV  4    // source views (views 1..4)
#define CH  12   // depths per thread in k_mlp
#define NCH 4    // 48/12
#define DB  8    // depth-block in k_warp (phase1/phase2 granularity)

// ---------------- tiny transform kernel ----------------

__device__ __forceinline__ void fuse_proj(const float* pm, float* P) {
  const float* E = pm;
  const float* K = pm + 16;
  for (int r = 0; r < 3; ++r)
    for (int c = 0; c < 4; ++c)
      P[r*4+c] = K[r*4+0]*E[0*4+c] + K[r*4+1]*E[1*4+c] + K[r*4+2]*E[2*4+c];
  for (int c = 0; c < 4; ++c) P[12+c] = E[12+c];
}

__device__ void invert4(const float* m, float* invOut) {
  float inv[16];
  inv[0]  =  m[5]*m[10]*m[15] - m[5]*m[11]*m[14] - m[9]*m[6]*m[15] + m[9]*m[7]*m[14] + m[13]*m[6]*m[11] - m[13]*m[7]*m[10];
  inv[4]  = -m[4]*m[10]*m[15] + m[4]*m[11]*m[14] + m[8]*m[6]*m[15] - m[8]*m[7]*m[14] - m[12]*m[6]*m[11] + m[12]*m[7]*m[10];
  inv[8]  =  m[4]*m[9]*m[15]  - m[4]*m[11]*m[13] - m[8]*m[5]*m[15] + m[8]*m[7]*m[13] + m[12]*m[5]*m[11] - m[12]*m[7]*m[9];
  inv[12] = -m[4]*m[9]*m[14]  + m[4]*m[10]*m[13] + m[8]*m[5]*m[14] - m[8]*m[6]*m[13] - m[12]*m[5]*m[10] + m[12]*m[6]*m[9];
  inv[1]  = -m[1]*m[10]*m[15] + m[1]*m[11]*m[14] + m[9]*m[2]*m[15] - m[9]*m[3]*m[14] - m[13]*m[2]*m[11] + m[13]*m[3]*m[10];
  inv[5]  =  m[0]*m[10]*m[15] - m[0]*m[11]*m[14] - m[8]*m[2]*m[15] + m[8]*m[3]*m[14] + m[12]*m[2]*m[11] - m[12]*m[3]*m[10];
  inv[9]  = -m[0]*m[9]*m[15]  + m[0]*m[11]*m[13] + m[8]*m[1]*m[15] - m[8]*m[3]*m[13] - m[12]*m[1]*m[11] + m[12]*m[3]*m[9];
  inv[13] =  m[0]*m[9]*m[14]  - m[0]*m[10]*m[13] - m[8]*m[1]*m[14] + m[8]*m[2]*m[13] + m[12]*m[1]*m[10] - m[12]*m[2]*m[9];
  inv[2]  =  m[1]*m[6]*m[15]  - m[1]*m[7]*m[14]  - m[5]*m[2]*m[15] + m[5]*m[3]*m[14] + m[13]*m[2]*m[7]  - m[13]*m[3]*m[6];
  inv[6]  = -m[0]*m[6]*m[15]  + m[0]*m[7]*m[14]  + m[4]*m[2]*m[15] - m[4]*m[3]*m[14] - m[12]*m[2]*m[7]  + m[12]*m[3]*m[6];
  inv[10] =  m[0]*m[5]*m[15]  - m[0]*m[7]*m[13]  - m[4]*m[1]*m[15] + m[4]*m[3]*m[13] + m[12]*m[1]*m[7]  - m[12]*m[3]*m[5];
  inv[14] = -m[0]*m[5]*m[14]  + m[0]*m[6]*m[13]  + m[4]*m[1]*m[14] - m[4]*m[2]*m[13] - m[12]*m[1]*m[6]  + m[12]*m[2]*m[5];
  inv[3]  = -m[1]*m[6]*m[11]  + m[1]*m[7]*m[10]  + m[5]*m[2]*m[11] - m[5]*m[3]*m[10] - m[9]*m[2]*m[7]   + m[9]*m[3]*m[6];
  inv[7]  =  m[0]*m[6]*m[11]  - m[0]*m[7]*m[10]  - m[4]*m[2]*m[11] + m[4]*m[3]*m[10] + m[8]*m[2]*m[7]   - m[8]*m[3]*m[6];
  inv[11] = -m[0]*m[5]*m[11]  + m[0]*m[7]*m[9]   + m[4]*m[1]*m[11] - m[4]*m[3]*m[9]  - m[8]*m[1]*m[7]   + m[8]*m[3]*m[5];
  inv[15] =  m[0]*m[5]*m[10]  - m[0]*m[6]*m[9]   - m[4]*m[1]*m[10] + m[4]*m[2]*m[9]  + m[8]*m[1]*m[6]   - m[8]*m[2]*m[5];
  float det = m[0]*inv[0] + m[1]*inv[4] + m[2]*inv[8] + m[3]*inv[12];
  det = 1.0f / det;
  for (int i = 0; i < 16; i++) invOut[i] = inv[i] * det;
}

// xf layout per src view v (0..3): [r00 r01 r02 r10 r11 r12 r20 r21 r22 t0 t1 t2]
__global__ void k_xform(const float* __restrict__ pm, float* __restrict__ xf) {
  if (blockIdx.x || threadIdx.x) return;
  float Pr[16], Pinv[16], Ps[16], M[16];
  fuse_proj(pm, Pr);
  invert4(Pr, Pinv);
  for (int v = 1; v <= NV; ++v) {
    fuse_proj(pm + v*32, Ps);
    for (int r = 0; r < 4; ++r)
      for (int c = 0; c < 4; ++c) {
        float a = 0.f;
        for (int k = 0; k < 4; ++k) a += Ps[r*4+k]*Pinv[k*4+c];
        M[r*4+c] = a;
      }
    float* o = xf + (v-1)*12;
    o[0]=M[0];  o[1]=M[1];  o[2]=M[2];
    o[3]=M[4];  o[4]=M[5];  o[5]=M[6];
    o[6]=M[8];  o[7]=M[9];  o[8]=M[10];
    o[9]=M[3];  o[10]=M[7]; o[11]=M[11];
  }
}

// ---------------- transpose (V,C,H,W) -> (V,HW,C) ----------------
// 8 lanes per pixel, each lane owns 4 channels -> fully coalesced stores.
__global__ void k_transpose(const float* __restrict__ feat, float* __restrict__ tf) {
  int idx = blockIdx.x*blockDim.x + threadIdx.x;   // (v, p, ch)
  if (idx >= 5*HW*8) return;
  int ch = idx & 7;
  int rest = idx >> 3;
  int p = rest % HW;
  int v = rest / HW;
  const float* src = feat + (size_t)v*C_*HW + (size_t)(ch*4)*HW + p;
  float4 t;
  t.x = src[0*HW];
  t.y = src[1*HW];
  t.z = src[2*HW];
  t.w = src[3*HW];
  *(float4*)(tf + ((size_t)v*HW + p)*C_ + ch*4) = t;
}

// ---------------- main warp + similarity kernel ----------------
// Wave = 8 pixels x 8 slots. Per 8-depth block:
//   phase 1: each lane computes the bilinear descriptor (4 corner offsets +
//            2 fracs) for ONE (pixel = lane>>3, depth = lane&7) item.
//            Invalid corners are redirected to a zeroed pad after tf, so
//            phase 2 needs no validity masks. px,py via rcp (tolerance-safe).
//   phase 2: per depth dd, 6 __shfl broadcasts from lane (lane&0x38)|dd give
//            the 8 channel-lanes their pixel's descriptor; 4 float4 loads
//            (same coalesced pattern as before: 8 contiguous lines/instr),
//            16 FMA dots, xor-shuffle reduce.
__global__ void __launch_bounds__(256)
k_warp(const float* __restrict__ tf, const float* __restrict__ dv,
       const float* __restrict__ xf, float* __restrict__ sim_all) {
  int tid = blockIdx.x*blockDim.x + threadIdx.x;
  int lane = threadIdx.x & 63;
  int ch = lane & 7;              // channel chunk in phase 2, depth slot in phase 1
  int wv = tid >> 6;              // global wave id: (v, pixel-group)
  const int PGPV = HW/8;          // 2560 pixel-groups per view
  int pg = wv % PGPV;
  int v  = wv / PGPV;
  int p  = pg*8 + ((lane>>3)&7);  // this lane's pixel (both phases)

  float xpix = (float)(p % W_);
  float ypix = (float)(p / W_);

  const float* M = xf + v*12;
  float rx = M[0]*xpix + M[1]*ypix + M[2];
  float ry = M[3]*xpix + M[4]*ypix + M[5];
  float rz = M[6]*xpix + M[7]*ypix + M[8];
  float t0 = M[9], t1 = M[10], t2 = M[11];

  // this lane's 4-channel slice of the ref feature
  float4 rfc = *(const float4*)(tf + (size_t)p*C_ + ch*4);
  const float* tfv = tf + (size_t)(v+1)*HW*C_;   // view base (phase-2 loads)
  const int ch4 = ch*4;
  const int ZOFF = (4-v)*HW*C_;   // element offset (from tfv) of the zero pad

  float* simv = sim_all + (size_t)v*D_*HW + p;

  for (int b = 0; b < D_/DB; ++b) {
    // ---- phase 1: one descriptor per lane ----
    int d1 = b*DB + ch;                       // this lane's depth
    float dep = dv[(size_t)d1*HW + p];
    float Z  = rz*dep + t2;
    float zr = __builtin_amdgcn_rcpf(Z);
    float px = (rx*dep + t0) * zr;
    float py = (ry*dep + t1) * zr;
    float x0f = floorf(px), y0f = floorf(py);
    float wx1 = px - x0f;
    float wy1 = py - y0f;
    int x0 = (int)x0f, y0 = (int)y0f;
    int x1 = x0 + 1,   y1 = y0 + 1;
    bool vx0 = ((unsigned)x0 <= (unsigned)(W_-1));
    bool vx1 = ((unsigned)x1 <= (unsigned)(W_-1));
    bool vy0 = ((unsigned)y0 <= (unsigned)(H_-1));
    bool vy1 = ((unsigned)y1 <= (unsigned)(H_-1));
    int cx0 = min(max(x0, 0), W_-1);
    int cx1 = min(max(x1, 0), W_-1);
    int cy0 = min(max(y0, 0), H_-1);
    int cy1 = min(max(y1, 0), H_-1);
    int r0 = cy0*W_, r1 = cy1*W_;
    int o00 = (vx0 && vy0) ? (r0+cx0)*C_ : ZOFF;
    int o01 = (vx1 && vy0) ? (r0+cx1)*C_ : ZOFF;
    int o10 = (vx0 && vy1) ? (r1+cx0)*C_ : ZOFF;
    int o11 = (vx1 && vy1) ? (r1+cx1)*C_ : ZOFF;

    // ---- phase 2: 8 depths, descriptor broadcast via shfl ----
    #pragma unroll
    for (int dd = 0; dd < DB; ++dd) {
      int src = (lane & 0x38) | dd;
      int  O00 = __shfl(o00, src);
      int  O01 = __shfl(o01, src);
      int  O10 = __shfl(o10, src);
      int  O11 = __shfl(o11, src);
      float fx1 = __shfl(wx1, src);
      float fy1 = __shfl(wy1, src);
      float fx0 = 1.0f - fx1, fy0 = 1.0f - fy1;
      float w00 = fx0*fy0, w01 = fx1*fy0, w10 = fx0*fy1, w11 = fx1*fy1;

      float4 a = *(const float4*)(tfv + O00 + ch4);
      float4 bq = *(const float4*)(tfv + O01 + ch4);
      float4 g = *(const float4*)(tfv + O10 + ch4);
      float4 e = *(const float4*)(tfv + O11 + ch4);

      float d00 = a.x*rfc.x  + a.y*rfc.y  + a.z*rfc.z  + a.w*rfc.w;
      float d01 = bq.x*rfc.x + bq.y*rfc.y + bq.z*rfc.z + bq.w*rfc.w;
      float d10 = g.x*rfc.x  + g.y*rfc.y  + g.z*rfc.z  + g.w*rfc.w;
      float d11 = e.x*rfc.x  + e.y*rfc.y  + e.z*rfc.z  + e.w*rfc.w;
      float s = w00*d00 + w01*d01 + w10*d10 + w11*d11;

      s += __shfl_xor(s, 1);
      s += __shfl_xor(s, 2);
      s += __shfl_xor(s, 4);

      if (ch == 0) simv[(size_t)(b*DB + dd)*HW] = s * (1.0f/(float)C_);
    }
  }
}

// ---------------- MLP over sim chunks: partial max of logit ----------------
__global__ void k_mlp(const float* __restrict__ sim_all,
                      const float* __restrict__ w0, const float* __restrict__ b0,
                      const float* __restrict__ w1, const float* __restrict__ b1,
                      const float* __restrict__ w2, const float* __restrict__ b2,
                      float* __restrict__ yp) {
  int idx = blockIdx.x*blockDim.x + threadIdx.x;   // (chunk, v, p), p fastest
  if (idx >= NV*NCH*HW) return;
  int p = idx % HW;
  int t = idx / HW;
  int v = t & 3;
  int chunk = t >> 2;

  float ymax = -3.0e38f;
  #pragma unroll
  for (int dd = 0; dd < CH; ++dd) {
    int d = chunk*CH + dd;
    float sim = sim_all[(size_t)(v*D_ + d)*HW + p];
    float h0[16];
    #pragma unroll
    for (int o = 0; o < 16; ++o) h0[o] = fmaxf(w0[o]*sim + b0[o], 0.0f);
    float yv = b2[0];
    #pragma unroll
    for (int j = 0; j < 8; ++j) {
      float a = b1[j];
      #pragma unroll
      for (int o = 0; o < 16; ++o) a += w1[j*16+o]*h0[o];
      yv += w2[j]*fmaxf(a, 0.0f);
    }
    ymax = fmaxf(ymax, yv);
  }
  yp[(size_t)(v*NCH + chunk)*HW + p] = ymax;
}

// ---------------- view weight: sigmoid(max over chunks) ----------------
__global__ void k_vw(const float* __restrict__ yp, float* __restrict__ vw,
                     float* __restrict__ out) {
  int idx = blockIdx.x*blockDim.x + threadIdx.x;   // (v,p)
  if (idx >= NV*HW) return;
  int p = idx % HW;
  int v = idx / HW;
  float m = yp[(size_t)(v*NCH+0)*HW + p];
  #pragma unroll
  for (int c = 1; c < NCH; ++c)
    m = fmaxf(m, yp[(size_t)(v*NCH+c)*HW + p]);
  float s = 1.0f / (1.0f + expf(-m));
  vw[(size_t)v*HW + p] = s;
  out[(size_t)(2*HW + D_*HW) + (size_t)v*HW + p] = s;
}

// ---------------- fuse views ----------------
__global__ void k_fuse(const float* __restrict__ sim_all, const float* __restrict__ vw,
                       float* __restrict__ fus) {
  int idx = blockIdx.x*blockDim.x + threadIdx.x;   // (d,p)
  if (idx >= D_*HW) return;
  int p = idx % HW;
  int d = idx / HW;
  float wsum = 1e-5f;
  float ssum = 0.0f;
  #pragma unroll
  for (int v = 0; v < NV; ++v) {
    float s = sim_all[(size_t)(v*D_ + d)*HW + p];
    float w = vw[(size_t)v*HW + p];
    ssum += s*w;
    wsum += w;
  }
  fus[(size_t)d*HW + p] = ssum / wsum;
}

// ---------------- 3x3x3 conv (cross-correlation, zero pad SAME) ----------------
__global__ void k_conv(const float* __restrict__ fus, const float* __restrict__ rw,
                       const float* __restrict__ rb, float* __restrict__ cost) {
  int idx = blockIdx.x*blockDim.x + threadIdx.x;   // (d,p)
  if (idx >= D_*HW) return;
  int p = idx % HW;
  int d = idx / HW;
  int x = p % W_;
  int y = p / W_;
  float acc = rb[0];
  #pragma unroll
  for (int kd = 0; kd < 3; ++kd) {
    int dz = d + kd - 1;
    if (dz < 0 || dz >= D_) continue;
    #pragma unroll
    for (int kh = 0; kh < 3; ++kh) {
      int yy = y + kh - 1;
      if (yy < 0 || yy >= H_) continue;
      #pragma unroll
      for (int kw = 0; kw < 3; ++kw) {
        int xx = x + kw - 1;
        if (xx < 0 || xx >= W_) continue;
        acc += fus[(size_t)dz*HW + yy*W_ + xx] * rw[(kd*3+kh)*3+kw];
      }
    }
  }
  cost[(size_t)d*HW + p] = acc;
}

// ---------------- softmax / argmax / outputs ----------------
__global__ void k_softmax(const float* __restrict__ cost, const float* __restrict__ dv,
                          float* __restrict__ out) {
  int p = blockIdx.x*blockDim.x + threadIdx.x;
  if (p >= HW) return;
  float vbuf[D_];
  #pragma unroll
  for (int d = 0; d < D_; ++d) vbuf[d] = cost[(size_t)d*HW + p];
  float vmax = vbuf[0];
  int am = 0;
  #pragma unroll
  for (int d = 1; d < D_; ++d) {
    if (vbuf[d] > vmax) { vmax = vbuf[d]; am = d; }
  }
  float sum = 0.0f;
  #pragma unroll
  for (int d = 0; d < D_; ++d) {
    float e = expf(vbuf[d] - vmax);
    vbuf[d] = e;
    sum += e;
  }
  float inv = 1.0f / sum;
  #pragma unroll
  for (int d = 0; d < D_; ++d) {
    out[(size_t)(2*HW) + (size_t)d*HW + p] = vbuf[d] * inv;   // prob
  }
  out[p] = dv[(size_t)am*HW + p];   // depth at argmax
  out[HW + p] = inv;                // conf = max prob = exp(0)/sum
}

// ---------------- launch ----------------
extern "C" void kernel_launch(void* const* d_in, const int* in_sizes, int n_in,
                              void* d_out, int out_size, void* d_ws, size_t ws_size,
                              hipStream_t stream) {
  const float* feat = (const float*)d_in[0];
  const float* pm   = (const float*)d_in[1];
  const float* dv   = (const float*)d_in[2];
  const float* w0   = (const float*)d_in[3];
  const float* b0   = (const float*)d_in[4];
  const float* w1   = (const float*)d_in[5];
  const float* b1   = (const float*)d_in[6];
  const float* w2   = (const float*)d_in[7];
  const float* b2   = (const float*)d_in[8];
  const float* rw   = (const float*)d_in[9];
  const float* rb   = (const float*)d_in[10];
  float* out = (float*)d_out;
  float* ws  = (float*)d_ws;

  // workspace layout (floats)
  float* xf   = ws;                  // 48 (pad 64)
  float* tf   = ws + 64;             // 5*HW*C + 64 zero-pad = 3,276,864 floats
  float* sim  = ws + 3276992;        // 4*48*HW = 3,932,160
  float* yp   = ws + 7209152;        // 4*4*HW = 327,680
  float* vw   = ws + 7536832;        // 4*HW = 81,920
  // tf is dead after k_warp: overlay fus and cost on it
  float* fus  = ws + 64;             // 48*HW = 983,040
  float* cost = ws + 64 + 983040;    // 48*HW = 983,040
  // high-water mark: ~7.62M floats = ~29 MB

  hipLaunchKernelGGL(k_xform, dim3(1), dim3(64), 0, stream, pm, xf);
  // zero pad after the 5 feature views (invalid-corner redirect target)
  hipMemsetAsync(tf + (size_t)5*HW*C_, 0, 64*sizeof(float), stream);
  hipLaunchKernelGGL(k_transpose, dim3((5*HW*8)/256), dim3(256), 0, stream, feat, tf);
  hipLaunchKernelGGL(k_warp, dim3((NV*HW*8)/256), dim3(256), 0, stream, tf, dv, xf, sim);
  hipLaunchKernelGGL(k_mlp, dim3((NV*NCH*HW)/256), dim3(256), 0, stream,
                     sim, w0, b0, w1, b1, w2, b2, yp);
  hipLaunchKernelGGL(k_vw, dim3((NV*HW)/256), dim3(256), 0, stream, yp, vw, out);
  hipLaunchKernelGGL(k_fuse, dim3((D_*HW)/256), dim3(256), 0, stream, sim, vw, fus);
  hipLaunchKernelGGL(k_conv, dim3((D_*HW)/256), dim3(256), 0, stream, fus, rw, rb, cost);
  hipLaunchKernelGGL(k_softmax, dim3(HW/256), dim3(256), 0, stream, cost, dv, out);
}

// Round 5
// 138.823 us; speedup vs baseline: 2.1428x; 1.0748x over previous
//
#include <hip/hip_runtime.h>
#include <hip/hip_bf16.h>
#include <math.h>

#define W_  160
#define H_  128
#define HW  20480
#define D_  48
#define C_  32
#define NV  4    // source views (views 1..4)
#define CH  12   // depths per thread in k_mlp
#define NCH 4    // 48/12
#define DB  8    // depth-block in k_warp

// conv/softmax tile
#define TX  16
#define TY  4
#define TXH 18
#define TYH 6
#define NCOL (TXH*TYH)   // 108

// ---------------- cross-lane helpers ----------------
template<int CTRL>
__device__ __forceinline__ float dpp_add(float s) {
  int t = __builtin_amdgcn_update_dpp(0, __float_as_int(s), CTRL, 0xF, 0xF, true);
  return s + __int_as_float(t);
}
__device__ __forceinline__ float swz_add4(float s) {
  int t = __builtin_amdgcn_ds_swizzle(__float_as_int(s), 0x101F);  // xor 4
  return s + __int_as_float(t);
}

// ---------------- tiny transform kernel ----------------

__device__ __forceinline__ void fuse_proj(const float* pm, float* P) {
  const float* E = pm;
  const float* K = pm + 16;
  for (int r = 0; r < 3; ++r)
    for (int c = 0; c < 4; ++c)
      P[r*4+c] = K[r*4+0]*E[0*4+c] + K[r*4+1]*E[1*4+c] + K[r*4+2]*E[2*4+c];
  for (int c = 0; c < 4; ++c) P[12+c] = E[12+c];
}

__device__ void invert4(const float* m, float* invOut) {
  float inv[16];
  inv[0]  =  m[5]*m[10]*m[15] - m[5]*m[11]*m[14] - m[9]*m[6]*m[15] + m[9]*m[7]*m[14] + m[13]*m[6]*m[11] - m[13]*m[7]*m[10];
  inv[4]  = -m[4]*m[10]*m[15] + m[4]*m[11]*m[14] + m[8]*m[6]*m[15] - m[8]*m[7]*m[14] - m[12]*m[6]*m[11] + m[12]*m[7]*m[10];
  inv[8]  =  m[4]*m[9]*m[15]  - m[4]*m[11]*m[13] - m[8]*m[5]*m[15] + m[8]*m[7]*m[13] + m[12]*m[5]*m[11] - m[12]*m[7]*m[9];
  inv[12] = -m[4]*m[9]*m[14]  + m[4]*m[10]*m[13] + m[8]*m[5]*m[14] - m[8]*m[6]*m[13] - m[12]*m[5]*m[10] + m[12]*m[6]*m[9];
  inv[1]  = -m[1]*m[10]*m[15] + m[1]*m[11]*m[14] + m[9]*m[2]*m[15] - m[9]*m[3]*m[14] - m[13]*m[2]*m[11] + m[13]*m[3]*m[10];
  inv[5]  =  m[0]*m[10]*m[15] - m[0]*m[11]*m[14] - m[8]*m[2]*m[15] + m[8]*m[3]*m[14] + m[12]*m[2]*m[11] - m[12]*m[3]*m[10];
  inv[9]  = -m[0]*m[9]*m[15]  + m[0]*m[11]*m[13] + m[8]*m[1]*m[15] - m[8]*m[3]*m[13] - m[12]*m[1]*m[11] + m[12]*m[3]*m[9];
  inv[13] =  m[0]*m[9]*m[14]  - m[0]*m[10]*m[13] - m[8]*m[1]*m[14] + m[8]*m[2]*m[13] + m[12]*m[1]*m[10] - m[12]*m[2]*m[9];
  inv[2]  =  m[1]*m[6]*m[15]  - m[1]*m[7]*m[14]  - m[5]*m[2]*m[15] + m[5]*m[3]*m[14] + m[13]*m[2]*m[7]  - m[13]*m[3]*m[6];
  inv[6]  = -m[0]*m[6]*m[15]  + m[0]*m[7]*m[14]  + m[4]*m[2]*m[15] - m[4]*m[3]*m[14] - m[12]*m[2]*m[7]  + m[12]*m[3]*m[6];
  inv[10] =  m[0]*m[5]*m[15]  - m[0]*m[7]*m[13]  - m[4]*m[1]*m[15] + m[4]*m[3]*m[13] + m[12]*m[1]*m[7]  - m[12]*m[3]*m[5];
  inv[14] = -m[0]*m[5]*m[14]  + m[0]*m[6]*m[13]  + m[4]*m[1]*m[14] - m[4]*m[2]*m[13] - m[12]*m[1]*m[6]  + m[12]*m[2]*m[5];
  inv[3]  = -m[1]*m[6]*m[11]  + m[1]*m[7]*m[10]  + m[5]*m[2]*m[11] - m[5]*m[3]*m[10] - m[9]*m[2]*m[7]   + m[9]*m[3]*m[6];
  inv[7]  =  m[0]*m[6]*m[11]  - m[0]*m[7]*m[10]  - m[4]*m[2]*m[11] + m[4]*m[3]*m[10] + m[8]*m[2]*m[7]   - m[8]*m[3]*m[6];
  inv[11] = -m[0]*m[5]*m[11]  + m[0]*m[7]*m[9]   + m[4]*m[1]*m[11] - m[4]*m[3]*m[9]  - m[8]*m[1]*m[7]   + m[8]*m[3]*m[5];
  inv[15] =  m[0]*m[5]*m[10]  - m[0]*m[6]*m[9]   - m[4]*m[1]*m[10] + m[4]*m[2]*m[9]  + m[8]*m[1]*m[6]   - m[8]*m[2]*m[5];
  float det = m[0]*inv[0] + m[1]*inv[4] + m[2]*inv[8] + m[3]*inv[12];
  det = 1.0f / det;
  for (int i = 0; i < 16; i++) invOut[i] = inv[i] * det;
}

// xf layout per src view v (0..3): [r00 r01 r02 r10 r11 r12 r20 r21 r22 t0 t1 t2]
__global__ void k_xform(const float* __restrict__ pm, float* __restrict__ xf) {
  if (blockIdx.x || threadIdx.x) return;
  float Pr[16], Pinv[16], Ps[16], M[16];
  fuse_proj(pm, Pr);
  invert4(Pr, Pinv);
  for (int v = 1; v <= NV; ++v) {
    fuse_proj(pm + v*32, Ps);
    for (int r = 0; r < 4; ++r)
      for (int c = 0; c < 4; ++c) {
        float a = 0.f;
        for (int k = 0; k < 4; ++k) a += Ps[r*4+k]*Pinv[k*4+c];
        M[r*4+c] = a;
      }
    float* o = xf + (v-1)*12;
    o[0]=M[0];  o[1]=M[1];  o[2]=M[2];
    o[3]=M[4];  o[4]=M[5];  o[5]=M[6];
    o[6]=M[8];  o[7]=M[9];  o[8]=M[10];
    o[9]=M[3];  o[10]=M[7]; o[11]=M[11];
  }
}

// ---------------- transpose (V,C,H,W) -> (V,HW,C) ----------------
__global__ void k_transpose(const float* __restrict__ feat, float* __restrict__ tf) {
  int idx = blockIdx.x*blockDim.x + threadIdx.x;   // (v, p, ch)
  if (idx >= 5*HW*8) return;
  int ch = idx & 7;
  int rest = idx >> 3;
  int p = rest % HW;
  int v = rest / HW;
  const float* src = feat + (size_t)v*C_*HW + (size_t)(ch*4)*HW + p;
  float4 t;
  t.x = src[0*HW];
  t.y = src[1*HW];
  t.z = src[2*HW];
  t.w = src[3*HW];
  *(float4*)(tf + ((size_t)v*HW + p)*C_ + ch*4) = t;
}

// ---------------- main warp + similarity kernel ----------------
// Wave = 8 pixels x 8 slots. Per 8-depth block:
//   phase 1: each lane computes the descriptor (4 corner BYTE offsets + 2
//            fracs) for ONE (pixel, depth) item, writes it to LDS once
//            (b128 + b64, xor-swizzled key -> bank-uniform).
//   phase 2: per depth, 2 LDS reads recover the descriptor (vs 6 bpermutes
//            before); 4 coalesced float4 corner loads; 16 FMA; reduce via
//            2 DPP quad-perm adds (VALU pipe) + 1 ds_swizzle xor-4.
__global__ void __launch_bounds__(256)
k_warp(const float* __restrict__ tf, const float* __restrict__ dv,
       const float* __restrict__ xf, float* __restrict__ sim_all) {
  __shared__ int4   dso[4][64];
  __shared__ float2 dsf[4][64];

  int tid = blockIdx.x*blockDim.x + threadIdx.x;
  int lane = threadIdx.x & 63;
  int wv = threadIdx.x >> 6;
  int ch = lane & 7;              // channel chunk (phase 2) / depth slot (phase 1)
  int pix = (lane >> 3) & 7;      // pixel within group
  int wvg = tid >> 6;             // global wave id
  const int PGPV = HW/8;
  int pg = wvg % PGPV;
  int v  = wvg / PGPV;
  int p  = pg*8 + pix;

  float xpix = (float)(p % W_);
  float ypix = (float)(p / W_);

  const float* M = xf + v*12;
  float rx = M[0]*xpix + M[1]*ypix + M[2];
  float ry = M[3]*xpix + M[4]*ypix + M[5];
  float rz = M[6]*xpix + M[7]*ypix + M[8];
  float t0 = M[9], t1 = M[10], t2 = M[11];

  float4 rfc = *(const float4*)(tf + (size_t)p*C_ + ch*4);
  const char* tfb = (const char*)(tf + (size_t)(v+1)*HW*C_);
  const int chb = ch*16;
  const int ZB = (4-v)*HW*C_*4;   // byte offset (from view base) of zero pad

  float* simv = sim_all + (size_t)v*D_*HW + p;

  for (int b = 0; b < D_/DB; ++b) {
    // ---- phase 1: one descriptor per lane, staged to LDS ----
    int d1 = b*DB + ch;
    float dep = dv[(size_t)d1*HW + p];
    float Z  = rz*dep + t2;
    float zr = __builtin_amdgcn_rcpf(Z);
    zr = zr * (2.0f - Z*zr);                 // Newton: ~1ulp
    float px = (rx*dep + t0) * zr;
    float py = (ry*dep + t1) * zr;
    float x0f = floorf(px), y0f = floorf(py);
    float wx1 = px - x0f;
    float wy1 = py - y0f;
    int x0 = (int)x0f, y0 = (int)y0f;
    int x1 = x0 + 1,   y1 = y0 + 1;
    bool vx0 = ((unsigned)x0 <= (unsigned)(W_-1));
    bool vx1 = ((unsigned)x1 <= (unsigned)(W_-1));
    bool vy0 = ((unsigned)y0 <= (unsigned)(H_-1));
    bool vy1 = ((unsigned)y1 <= (unsigned)(H_-1));
    int cx0 = min(max(x0, 0), W_-1);
    int cx1 = min(max(x1, 0), W_-1);
    int cy0 = min(max(y0, 0), H_-1);
    int cy1 = min(max(y1, 0), H_-1);
    int r0 = cy0*W_, r1 = cy1*W_;
    int o00 = (vx0 && vy0) ? (r0+cx0)*(C_*4) : ZB;
    int o01 = (vx1 && vy0) ? (r0+cx1)*(C_*4) : ZB;
    int o10 = (vx0 && vy1) ? (r1+cx0)*(C_*4) : ZB;
    int o11 = (vx1 && vy1) ? (r1+cx1)*(C_*4) : ZB;

    int key = (ch<<3) | (pix ^ ch);          // bank-uniform for write & read
    dso[wv][key] = make_int4(o00, o01, o10, o11);
    dsf[wv][key] = make_float2(wx1, wy1);

    // ---- phase 2: 8 depths; descriptor via 2 LDS reads ----
    #pragma unroll
    for (int dd = 0; dd < DB; ++dd) {
      int it = (dd<<3) | (pix ^ dd);
      int4   O = dso[wv][it];
      float2 F = dsf[wv][it];
      float fx1 = F.x, fy1 = F.y;
      float fx0 = 1.0f - fx1, fy0 = 1.0f - fy1;
      float w00 = fx0*fy0, w01 = fx1*fy0, w10 = fx0*fy1, w11 = fx1*fy1;

      float4 a  = *(const float4*)(tfb + (O.x + chb));
      float4 bq = *(const float4*)(tfb + (O.y + chb));
      float4 g  = *(const float4*)(tfb + (O.z + chb));
      float4 e  = *(const float4*)(tfb + (O.w + chb));

      float d00 = a.x*rfc.x  + a.y*rfc.y  + a.z*rfc.z  + a.w*rfc.w;
      float d01 = bq.x*rfc.x + bq.y*rfc.y + bq.z*rfc.z + bq.w*rfc.w;
      float d10 = g.x*rfc.x  + g.y*rfc.y  + g.z*rfc.z  + g.w*rfc.w;
      float d11 = e.x*rfc.x  + e.y*rfc.y  + e.z*rfc.z  + e.w*rfc.w;
      float s = w00*d00 + w01*d01 + w10*d10 + w11*d11;

      s = dpp_add<0xB1>(s);   // xor 1 (quad_perm [1,0,3,2])
      s = dpp_add<0x4E>(s);   // xor 2 (quad_perm [2,3,0,1])
      s = swz_add4(s);        // xor 4 (ds_swizzle)

      if (ch == 0) simv[(size_t)(b*DB + dd)*HW] = s * (1.0f/(float)C_);
    }
  }
}

// ---------------- MLP over sim chunks: partial max of logit ----------------
__global__ void k_mlp(const float* __restrict__ sim_all,
                      const float* __restrict__ w0, const float* __restrict__ b0,
                      const float* __restrict__ w1, const float* __restrict__ b1,
                      const float* __restrict__ w2, const float* __restrict__ b2,
                      float* __restrict__ yp) {
  int idx = blockIdx.x*blockDim.x + threadIdx.x;   // (chunk, v, p), p fastest
  if (idx >= NV*NCH*HW) return;
  int p = idx % HW;
  int t = idx / HW;
  int v = t & 3;
  int chunk = t >> 2;

  float ymax = -3.0e38f;
  #pragma unroll
  for (int dd = 0; dd < CH; ++dd) {
    int d = chunk*CH + dd;
    float sim = sim_all[(size_t)(v*D_ + d)*HW + p];
    float h0[16];
    #pragma unroll
    for (int o = 0; o < 16; ++o) h0[o] = fmaxf(w0[o]*sim + b0[o], 0.0f);
    float yv = b2[0];
    #pragma unroll
    for (int j = 0; j < 8; ++j) {
      float a = b1[j];
      #pragma unroll
      for (int o = 0; o < 16; ++o) a += w1[j*16+o]*h0[o];
      yv += w2[j]*fmaxf(a, 0.0f);
    }
    ymax = fmaxf(ymax, yv);
  }
  yp[(size_t)(v*NCH + chunk)*HW + p] = ymax;
}

// ---------------- view weight: sigmoid(max over chunks) ----------------
__global__ void k_vw(const float* __restrict__ yp, float* __restrict__ vw,
                     float* __restrict__ out) {
  int idx = blockIdx.x*blockDim.x + threadIdx.x;   // (v,p)
  if (idx >= NV*HW) return;
  int p = idx % HW;
  int v = idx / HW;
  float m = yp[(size_t)(v*NCH+0)*HW + p];
  #pragma unroll
  for (int c = 1; c < NCH; ++c)
    m = fmaxf(m, yp[(size_t)(v*NCH+c)*HW + p]);
  float s = 1.0f / (1.0f + expf(-m));
  vw[(size_t)v*HW + p] = s;
  out[(size_t)(2*HW + D_*HW) + (size_t)v*HW + p] = s;
}

// ---------------- fused: fuse + 3x3x3 conv + softmax/argmax ----------------
// One block = 16x4 pixel tile. Fused volume (with halo) built in LDS, conv
// with sliding depth-register window, softmax from LDS. No fus/cost globals.
__global__ void __launch_bounds__(256)
k_fct(const float* __restrict__ sim_all, const float* __restrict__ vw,
      const float* __restrict__ rw, const float* __restrict__ rb,
      const float* __restrict__ dv, float* __restrict__ out) {
  __shared__ float sfus[D_][TYH][TXH+1];
  __shared__ float scost[D_][64];
  __shared__ float svw[NV][NCOL];
  __shared__ float sinvw[NCOL];
  __shared__ int   sgpc[NCOL];

  int tid = threadIdx.x;
  int gx0 = blockIdx.x*TX;
  int gy0 = blockIdx.y*TY;

  // phase A: per-column view weights / inverse wsum / clamped pixel index
  if (tid < NCOL) {
    int yy = tid / TXH, xx = tid % TXH;
    int gy = gy0 + yy - 1, gx = gx0 + xx - 1;
    bool valid = (gx >= 0) && (gx < W_) && (gy >= 0) && (gy < H_);
    int gp = min(max(gy,0),H_-1)*W_ + min(max(gx,0),W_-1);
    sgpc[tid] = gp;
    float a0 = vw[0*HW+gp], a1 = vw[1*HW+gp], a2 = vw[2*HW+gp], a3 = vw[3*HW+gp];
    float inv = valid ? 1.0f/(1e-5f + a0+a1+a2+a3) : 0.0f;
    if (!valid) { a0=a1=a2=a3=0.f; }
    svw[0][tid]=a0; svw[1][tid]=a1; svw[2][tid]=a2; svw[3][tid]=a3;
    sinvw[tid] = inv;
  }
  __syncthreads();

  // phase B: fill fused volume tile (invalid columns auto-zero via weights)
  for (int j = tid; j < D_*NCOL; j += 256) {
    int d = j / NCOL, r = j % NCOL;
    int gp = sgpc[r];
    float s0 = sim_all[(size_t)(0*D_+d)*HW + gp];
    float s1 = sim_all[(size_t)(1*D_+d)*HW + gp];
    float s2 = sim_all[(size_t)(2*D_+d)*HW + gp];
    float s3 = sim_all[(size_t)(3*D_+d)*HW + gp];
    float val = (s0*svw[0][r] + s1*svw[1][r] + s2*svw[2][r] + s3*svw[3][r]) * sinvw[r];
    int yy = r / TXH, xx = r % TXH;
    sfus[d][yy][xx] = val;
  }
  __syncthreads();

  // phase C: 3x3x3 conv; thread = (pixel, depth-group of 12)
  {
    int pid = tid & 63;
    int dg  = tid >> 6;
    int px = pid & 15, py = pid >> 4;
    float kw[27];
    #pragma unroll
    for (int i = 0; i < 27; ++i) kw[i] = rw[i];
    float bias = rb[0];

    float pm1[9], p0[9], pp1[9];
    int d0 = dg*12;
    #pragma unroll
    for (int i = 0; i < 9; ++i) {
      int ky = i/3, kx = i%3;
      pm1[i] = (d0 > 0) ? sfus[d0-1][py+ky][px+kx] : 0.0f;
      p0[i]  = sfus[d0][py+ky][px+kx];
    }
    #pragma unroll
    for (int k = 0; k < 12; ++k) {
      int d = d0 + k;
      #pragma unroll
      for (int i = 0; i < 9; ++i) {
        int ky = i/3, kx = i%3;
        pp1[i] = (d+1 < D_) ? sfus[d+1][py+ky][px+kx] : 0.0f;
      }
      float acc = bias;
      #pragma unroll
      for (int i = 0; i < 9; ++i) acc += pm1[i]*kw[i];
      #pragma unroll
      for (int i = 0; i < 9; ++i) acc += p0[i]*kw[9+i];
      #pragma unroll
      for (int i = 0; i < 9; ++i) acc += pp1[i]*kw[18+i];
      scost[d][pid] = acc;
      #pragma unroll
      for (int i = 0; i < 9; ++i) { pm1[i] = p0[i]; p0[i] = pp1[i]; }
    }
  }
  __syncthreads();

  // phase D: softmax / argmax / outputs, one thread per pixel
  if (tid < 64) {
    int gx = gx0 + (tid & 15), gy = gy0 + (tid >> 4);
    int gp = gy*W_ + gx;
    float vmax = scost[0][tid];
    int am = 0;
    #pragma unroll
    for (int d = 1; d < D_; ++d) {
      float c = scost[d][tid];
      if (c > vmax) { vmax = c; am = d; }
    }
    float sum = 0.0f;
    #pragma unroll
    for (int d = 0; d < D_; ++d) sum += expf(scost[d][tid] - vmax);
    float inv = 1.0f / sum;
    #pragma unroll
    for (int d = 0; d < D_; ++d)
      out[(size_t)(2*HW) + (size_t)d*HW + gp] = expf(scost[d][tid] - vmax) * inv;
    out[gp] = dv[(size_t)am*HW + gp];
    out[HW + gp] = inv;
  }
}

// ---------------- launch ----------------
extern "C" void kernel_launch(void* const* d_in, const int* in_sizes, int n_in,
                              void* d_out, int out_size, void* d_ws, size_t ws_size,
                              hipStream_t stream) {
  const float* feat = (const float*)d_in[0];
  const float* pm   = (const float*)d_in[1];
  const float* dv   = (const float*)d_in[2];
  const float* w0   = (const float*)d_in[3];
  const float* b0   = (const float*)d_in[4];
  const float* w1   = (const float*)d_in[5];
  const float* b1   = (const float*)d_in[6];
  const float* w2   = (const float*)d_in[7];
  const float* b2   = (const float*)d_in[8];
  const float* rw   = (const float*)d_in[9];
  const float* rb   = (const float*)d_in[10];
  float* out = (float*)d_out;
  float* ws  = (float*)d_ws;

  // workspace layout (floats)
  float* xf   = ws;                  // 48 (pad 64)
  float* tf   = ws + 64;             // 5*HW*C + 64 zero-pad = 3,276,864 floats
  float* sim  = ws + 3276992;        // 4*48*HW = 3,932,160
  float* yp   = ws + 7209152;        // 4*4*HW = 327,680
  float* vw   = ws + 7536832;        // 4*HW = 81,920
  // high-water mark: ~7.62M floats = ~29 MB

  hipLaunchKernelGGL(k_xform, dim3(1), dim3(64), 0, stream, pm, xf);
  hipMemsetAsync(tf + (size_t)5*HW*C_, 0, 64*sizeof(float), stream);
  hipLaunchKernelGGL(k_transpose, dim3((5*HW*8)/256), dim3(256), 0, stream, feat, tf);
  hipLaunchKernelGGL(k_warp, dim3((NV*HW*8)/256), dim3(256), 0, stream, tf, dv, xf, sim);
  hipLaunchKernelGGL(k_mlp, dim3((NV*NCH*HW)/256), dim3(256), 0, stream,
                     sim, w0, b0, w1, b1, w2, b2, yp);
  hipLaunchKernelGGL(k_vw, dim3((NV*HW)/256), dim3(256), 0, stream, yp, vw, out);
  hipLaunchKernelGGL(k_fct, dim3(W_/TX, H_/TY), dim3(256), 0, stream,
                     sim, vw, rw, rb, dv, out);
}

// Round 6
// 122.418 us; speedup vs baseline: 2.4300x; 1.1340x over previous
//
#include <hip/hip_runtime.h>
#include <hip/hip_bf16.h>
#include <math.h>

#define W_  160
#define H_  128
#define HW  20480
#define D_  48
#define C_  32
#define NV  4    // source views (views 1..4)
#define CH  24   // depths per thread in k_mlp
#define NCH 2    // 48/24
#define DB  8    // depth-block in k_warp

// conv/softmax tile
#define TX  16
#define TY  4
#define TXH 18
#define TYH 6
#define NCOL (TXH*TYH)   // 108

// ---------------- cross-lane helpers ----------------
template<int CTRL>
__device__ __forceinline__ float dpp_add(float s) {
  int t = __builtin_amdgcn_update_dpp(0, __float_as_int(s), CTRL, 0xF, 0xF, true);
  return s + __int_as_float(t);
}
__device__ __forceinline__ float swz_add4(float s) {
  int t = __builtin_amdgcn_ds_swizzle(__float_as_int(s), 0x101F);  // xor 4
  return s + __int_as_float(t);
}

// ---------------- tiny transform kernel ----------------

__device__ __forceinline__ void fuse_proj(const float* pm, float* P) {
  const float* E = pm;
  const float* K = pm + 16;
  for (int r = 0; r < 3; ++r)
    for (int c = 0; c < 4; ++c)
      P[r*4+c] = K[r*4+0]*E[0*4+c] + K[r*4+1]*E[1*4+c] + K[r*4+2]*E[2*4+c];
  for (int c = 0; c < 4; ++c) P[12+c] = E[12+c];
}

__device__ void invert4(const float* m, float* invOut) {
  float inv[16];
  inv[0]  =  m[5]*m[10]*m[15] - m[5]*m[11]*m[14] - m[9]*m[6]*m[15] + m[9]*m[7]*m[14] + m[13]*m[6]*m[11] - m[13]*m[7]*m[10];
  inv[4]  = -m[4]*m[10]*m[15] + m[4]*m[11]*m[14] + m[8]*m[6]*m[15] - m[8]*m[7]*m[14] - m[12]*m[6]*m[11] + m[12]*m[7]*m[10];
  inv[8]  =  m[4]*m[9]*m[15]  - m[4]*m[11]*m[13] - m[8]*m[5]*m[15] + m[8]*m[7]*m[13] + m[12]*m[5]*m[11] - m[12]*m[7]*m[9];
  inv[12] = -m[4]*m[9]*m[14]  + m[4]*m[10]*m[13] + m[8]*m[5]*m[14] - m[8]*m[6]*m[13] - m[12]*m[5]*m[10] + m[12]*m[6]*m[9];
  inv[1]  = -m[1]*m[10]*m[15] + m[1]*m[11]*m[14] + m[9]*m[2]*m[15] - m[9]*m[3]*m[14] - m[13]*m[2]*m[11] + m[13]*m[3]*m[10];
  inv[5]  =  m[0]*m[10]*m[15] - m[0]*m[11]*m[14] - m[8]*m[2]*m[15] + m[8]*m[3]*m[14] + m[12]*m[2]*m[11] - m[12]*m[3]*m[10];
  inv[9]  = -m[0]*m[9]*m[15]  + m[0]*m[11]*m[13] + m[8]*m[1]*m[15] - m[8]*m[3]*m[13] - m[12]*m[1]*m[11] + m[12]*m[3]*m[9];
  inv[13] =  m[0]*m[9]*m[14]  - m[0]*m[10]*m[13] - m[8]*m[1]*m[14] + m[8]*m[2]*m[13] + m[12]*m[1]*m[10] - m[12]*m[2]*m[9];
  inv[2]  =  m[1]*m[6]*m[15]  - m[1]*m[7]*m[14]  - m[5]*m[2]*m[15] + m[5]*m[3]*m[14] + m[13]*m[2]*m[7]  - m[13]*m[3]*m[6];
  inv[6]  = -m[0]*m[6]*m[15]  + m[0]*m[7]*m[14]  + m[4]*m[2]*m[15] - m[4]*m[3]*m[14] - m[12]*m[2]*m[7]  + m[12]*m[3]*m[6];
  inv[10] =  m[0]*m[5]*m[15]  - m[0]*m[7]*m[13]  - m[4]*m[1]*m[15] + m[4]*m[3]*m[13] + m[12]*m[1]*m[7]  - m[12]*m[3]*m[5];
  inv[14] = -m[0]*m[5]*m[14]  + m[0]*m[6]*m[13]  + m[4]*m[1]*m[14] - m[4]*m[2]*m[13] - m[12]*m[1]*m[6]  + m[12]*m[2]*m[5];
  inv[3]  = -m[1]*m[6]*m[11]  + m[1]*m[7]*m[10]  + m[5]*m[2]*m[11] - m[5]*m[3]*m[10] - m[9]*m[2]*m[7]   + m[9]*m[3]*m[6];
  inv[7]  =  m[0]*m[6]*m[11]  - m[0]*m[7]*m[10]  - m[4]*m[2]*m[11] + m[4]*m[3]*m[10] + m[8]*m[2]*m[7]   - m[8]*m[3]*m[6];
  inv[11] = -m[0]*m[5]*m[11]  + m[0]*m[7]*m[9]   + m[4]*m[1]*m[11] - m[4]*m[3]*m[9]  - m[8]*m[1]*m[7]   + m[8]*m[3]*m[5];
  inv[15] =  m[0]*m[5]*m[10]  - m[0]*m[6]*m[9]   - m[4]*m[1]*m[10] + m[4]*m[2]*m[9]  + m[8]*m[1]*m[6]   - m[8]*m[2]*m[5];
  float det = m[0]*inv[0] + m[1]*inv[4] + m[2]*inv[8] + m[3]*inv[12];
  det = 1.0f / det;
  for (int i = 0; i < 16; i++) invOut[i] = inv[i] * det;
}

// xf layout per src view v (0..3): [r00 r01 r02 r10 r11 r12 r20 r21 r22 t0 t1 t2]
__global__ void k_xform(const float* __restrict__ pm, float* __restrict__ xf) {
  if (blockIdx.x || threadIdx.x) return;
  float Pr[16], Pinv[16], Ps[16], M[16];
  fuse_proj(pm, Pr);
  invert4(Pr, Pinv);
  for (int v = 1; v <= NV; ++v) {
    fuse_proj(pm + v*32, Ps);
    for (int r = 0; r < 4; ++r)
      for (int c = 0; c < 4; ++c) {
        float a = 0.f;
        for (int k = 0; k < 4; ++k) a += Ps[r*4+k]*Pinv[k*4+c];
        M[r*4+c] = a;
      }
    float* o = xf + (v-1)*12;
    o[0]=M[0];  o[1]=M[1];  o[2]=M[2];
    o[3]=M[4];  o[4]=M[5];  o[5]=M[6];
    o[6]=M[8];  o[7]=M[9];  o[8]=M[10];
    o[9]=M[3];  o[10]=M[7]; o[11]=M[11];
  }
}

// ---------------- transpose (V,C,H,W) -> (V,HW,C), LDS-tiled ----------------
// Both global sides coalesced: loads are 256B-contiguous rows of a channel
// plane; stores are 1KB-contiguous (p,c) vectors.
__global__ void __launch_bounds__(256)
k_transpose(const float* __restrict__ feat, float* __restrict__ tf) {
  __shared__ float tile[C_][64+1];
  int v  = blockIdx.y;
  int p0 = blockIdx.x * 64;
  int t  = threadIdx.x;

  int pl = t & 63;
  int cg = t >> 6;            // 0..3
  const float* src = feat + (size_t)v*C_*HW + p0 + pl;
  #pragma unroll
  for (int k = 0; k < 8; ++k) {
    int c = cg*8 + k;
    tile[c][pl] = src[(size_t)c*HW];
  }
  __syncthreads();

  int pp = t >> 2;            // pixel 0..63
  int co = (t & 3) * 8;       // channel offset
  float4 a, b;
  a.x = tile[co+0][pp]; a.y = tile[co+1][pp]; a.z = tile[co+2][pp]; a.w = tile[co+3][pp];
  b.x = tile[co+4][pp]; b.y = tile[co+5][pp]; b.z = tile[co+6][pp]; b.w = tile[co+7][pp];
  float* dst = tf + ((size_t)v*HW + p0 + pp)*C_ + co;
  *(float4*)dst = a;
  *(float4*)(dst+4) = b;
}

// ---------------- main warp + similarity kernel ----------------
// Wave = 8 pixels x 8 slots. Per 8-depth block:
//   phase 1: each lane computes the descriptor (4 corner BYTE offsets + 2
//            fracs) for ONE (pixel, depth) item with EXACT division
//            (argmax-tie safety), writes it to LDS once (xor-swizzled).
//   phase 2: per depth, 2 LDS reads recover the descriptor; if no lane's
//            corner set changed vs the previous depth (epipolar span over
//            48 depths is only 1-4 px), skip the 4 corner loads + dots and
//            reuse the cached per-lane partial dots (wave-uniform branch).
__global__ void __launch_bounds__(256)
k_warp(const float* __restrict__ tf, const float* __restrict__ dv,
       const float* __restrict__ xf, float* __restrict__ sim_all) {
  __shared__ int4   dso[4][64];
  __shared__ float2 dsf[4][64];

  int lane = threadIdx.x & 63;
  int wv = threadIdx.x >> 6;
  int ch = lane & 7;              // channel chunk (phase 2) / depth slot (phase 1)
  int pix = (lane >> 3) & 7;      // pixel within group
  int wvg = __builtin_amdgcn_readfirstlane((blockIdx.x*256 + threadIdx.x) >> 6);
  const int PGPV = HW/8;
  int pg = wvg % PGPV;
  int v  = wvg / PGPV;
  int p  = pg*8 + pix;

  float xpix = (float)(p % W_);
  float ypix = (float)(p / W_);

  const float* M = xf + v*12;
  float rx = M[0]*xpix + M[1]*ypix + M[2];
  float ry = M[3]*xpix + M[4]*ypix + M[5];
  float rz = M[6]*xpix + M[7]*ypix + M[8];
  float t0 = M[9], t1 = M[10], t2 = M[11];

  float4 rfc = *(const float4*)(tf + (size_t)p*C_ + ch*4);
  const char* tfb = (const char*)(tf + (size_t)(v+1)*HW*C_);
  const int chb = ch*16;
  const int ZB = (4-v)*HW*C_*4;   // byte offset (from view base) of zero pad

  float* simv = sim_all + (size_t)v*D_*HW + p;

  int4 P = make_int4(-1,-1,-1,-1);
  float d00 = 0.f, d01 = 0.f, d10 = 0.f, d11 = 0.f;

  for (int b = 0; b < D_/DB; ++b) {
    // ---- phase 1: one descriptor per lane, staged to LDS ----
    int d1 = b*DB + ch;
    float dep = dv[(size_t)d1*HW + p];
    float Z  = rz*dep + t2;
    float px = (rx*dep + t0) / Z;       // exact IEEE divide (argmax safety)
    float py = (ry*dep + t1) / Z;
    float x0f = floorf(px), y0f = floorf(py);
    float wx1 = px - x0f;
    float wy1 = py - y0f;
    int x0 = (int)x0f, y0 = (int)y0f;
    int x1 = x0 + 1,   y1 = y0 + 1;
    bool vx0 = ((unsigned)x0 <= (unsigned)(W_-1));
    bool vx1 = ((unsigned)x1 <= (unsigned)(W_-1));
    bool vy0 = ((unsigned)y0 <= (unsigned)(H_-1));
    bool vy1 = ((unsigned)y1 <= (unsigned)(H_-1));
    int cx0 = min(max(x0, 0), W_-1);
    int cx1 = min(max(x1, 0), W_-1);
    int cy0 = min(max(y0, 0), H_-1);
    int cy1 = min(max(y1, 0), H_-1);
    int r0 = cy0*W_, r1 = cy1*W_;
    int o00 = (vx0 && vy0) ? (r0+cx0)*(C_*4) : ZB;
    int o01 = (vx1 && vy0) ? (r0+cx1)*(C_*4) : ZB;
    int o10 = (vx0 && vy1) ? (r1+cx0)*(C_*4) : ZB;
    int o11 = (vx1 && vy1) ? (r1+cx1)*(C_*4) : ZB;

    int key = (ch<<3) | (pix ^ ch);          // bank-uniform for write & read
    dso[wv][key] = make_int4(o00, o01, o10, o11);
    dsf[wv][key] = make_float2(wx1, wy1);

    // ---- phase 2: 8 depths; descriptor via 2 LDS reads ----
    #pragma unroll
    for (int dd = 0; dd < DB; ++dd) {
      int it = (dd<<3) | (pix ^ dd);
      int4   O = dso[wv][it];
      float2 F = dsf[wv][it];
      float fx1 = F.x, fy1 = F.y;
      float fx0 = 1.0f - fx1, fy0 = 1.0f - fy1;
      float w00 = fx0*fy0, w01 = fx1*fy0, w10 = fx0*fy1, w11 = fx1*fy1;

      bool moved = (O.x != P.x) || (O.y != P.y) || (O.z != P.z) || (O.w != P.w);
      if (__any(moved)) {
        float4 a  = *(const float4*)(tfb + (O.x + chb));
        float4 bq = *(const float4*)(tfb + (O.y + chb));
        float4 g  = *(const float4*)(tfb + (O.z + chb));
        float4 e  = *(const float4*)(tfb + (O.w + chb));
        d00 = a.x*rfc.x  + a.y*rfc.y  + a.z*rfc.z  + a.w*rfc.w;
        d01 = bq.x*rfc.x + bq.y*rfc.y + bq.z*rfc.z + bq.w*rfc.w;
        d10 = g.x*rfc.x  + g.y*rfc.y  + g.z*rfc.z  + g.w*rfc.w;
        d11 = e.x*rfc.x  + e.y*rfc.y  + e.z*rfc.z  + e.w*rfc.w;
      }
      P = O;

      float s = w00*d00 + w01*d01 + w10*d10 + w11*d11;
      s = dpp_add<0xB1>(s);   // xor 1 (quad_perm [1,0,3,2])
      s = dpp_add<0x4E>(s);   // xor 2 (quad_perm [2,3,0,1])
      s = swz_add4(s);        // xor 4 (ds_swizzle)

      if (ch == 0) simv[(size_t)(b*DB + dd)*HW] = s * (1.0f/(float)C_);
    }
  }
}

// ---------------- MLP over sim: per-view chunk max of logit ----------------
__global__ void k_mlp(const float* __restrict__ sim_all,
                      const float* __restrict__ w0, const float* __restrict__ b0,
                      const float* __restrict__ w1, const float* __restrict__ b1,
                      const float* __restrict__ w2, const float* __restrict__ b2,
                      float* __restrict__ yp) {
  int idx = blockIdx.x*blockDim.x + threadIdx.x;   // (chunk, v, p), p fastest
  if (idx >= NV*NCH*HW) return;
  int p = idx % HW;
  int t = idx / HW;
  int v = t & 3;
  int chunk = t >> 2;

  float ymax = -3.0e38f;
  #pragma unroll 2
  for (int dd = 0; dd < CH; ++dd) {
    int d = chunk*CH + dd;
    float sim = sim_all[(size_t)(v*D_ + d)*HW + p];
    float h0[16];
    #pragma unroll
    for (int o = 0; o < 16; ++o) h0[o] = fmaxf(w0[o]*sim + b0[o], 0.0f);
    float yv = b2[0];
    #pragma unroll
    for (int j = 0; j < 8; ++j) {
      float a = b1[j];
      #pragma unroll
      for (int o = 0; o < 16; ++o) a += w1[j*16+o]*h0[o];
      yv += w2[j]*fmaxf(a, 0.0f);
    }
    ymax = fmaxf(ymax, yv);
  }
  yp[(size_t)(v*NCH + chunk)*HW + p] = ymax;
}

// ---------------- fused: vw + fuse + 3x3x3 conv + softmax/argmax ----------------
// One block = 16x4 pixel tile. Phase A combines the per-view chunk maxima into
// sigmoid view weights (also emitted as output in phase D); fused volume with
// halo built in LDS; conv with sliding depth-register window; softmax in LDS.
__global__ void __launch_bounds__(256)
k_fct(const float* __restrict__ sim_all, const float* __restrict__ yp,
      const float* __restrict__ rw, const float* __restrict__ rb,
      const float* __restrict__ dv, float* __restrict__ out) {
  __shared__ float sfus[D_][TYH][TXH+1];
  __shared__ float scost[D_][64];
  __shared__ float svw[NV][NCOL];
  __shared__ float sinvw[NCOL];
  __shared__ int   sgpc[NCOL];

  int tid = threadIdx.x;
  int gx0 = blockIdx.x*TX;
  int gy0 = blockIdx.y*TY;

  // phase A: per-column view weights / inverse wsum / clamped pixel index
  if (tid < NCOL) {
    int yy = tid / TXH, xx = tid % TXH;
    int gy = gy0 + yy - 1, gx = gx0 + xx - 1;
    bool valid = (gx >= 0) && (gx < W_) && (gy >= 0) && (gy < H_);
    int gp = min(max(gy,0),H_-1)*W_ + min(max(gx,0),W_-1);
    sgpc[tid] = gp;
    float a0 = 1.0f/(1.0f + expf(-fmaxf(yp[0*HW+gp], yp[1*HW+gp])));
    float a1 = 1.0f/(1.0f + expf(-fmaxf(yp[2*HW+gp], yp[3*HW+gp])));
    float a2 = 1.0f/(1.0f + expf(-fmaxf(yp[4*HW+gp], yp[5*HW+gp])));
    float a3 = 1.0f/(1.0f + expf(-fmaxf(yp[6*HW+gp], yp[7*HW+gp])));
    float inv = valid ? 1.0f/(1e-5f + a0+a1+a2+a3) : 0.0f;
    if (!valid) { a0=a1=a2=a3=0.f; }
    svw[0][tid]=a0; svw[1][tid]=a1; svw[2][tid]=a2; svw[3][tid]=a3;
    sinvw[tid] = inv;
  }
  __syncthreads();

  // phase B: fill fused volume tile (invalid columns auto-zero via weights)
  for (int j = tid; j < D_*NCOL; j += 256) {
    int d = j / NCOL, r = j % NCOL;
    int gp = sgpc[r];
    float s0 = sim_all[(size_t)(0*D_+d)*HW + gp];
    float s1 = sim_all[(size_t)(1*D_+d)*HW + gp];
    float s2 = sim_all[(size_t)(2*D_+d)*HW + gp];
    float s3 = sim_all[(size_t)(3*D_+d)*HW + gp];
    float val = (s0*svw[0][r] + s1*svw[1][r] + s2*svw[2][r] + s3*svw[3][r]) * sinvw[r];
    int yy = r / TXH, xx = r % TXH;
    sfus[d][yy][xx] = val;
  }
  __syncthreads();

  // phase C: 3x3x3 conv; thread = (pixel, depth-group of 12)
  {
    int pid = tid & 63;
    int dg  = tid >> 6;
    int px = pid & 15, py = pid >> 4;
    float kw[27];
    #pragma unroll
    for (int i = 0; i < 27; ++i) kw[i] = rw[i];
    float bias = rb[0];

    float pm1[9], p0[9], pp1[9];
    int d0 = dg*12;
    #pragma unroll
    for (int i = 0; i < 9; ++i) {
      int ky = i/3, kx = i%3;
      pm1[i] = (d0 > 0) ? sfus[d0-1][py+ky][px+kx] : 0.0f;
      p0[i]  = sfus[d0][py+ky][px+kx];
    }
    #pragma unroll
    for (int k = 0; k < 12; ++k) {
      int d = d0 + k;
      #pragma unroll
      for (int i = 0; i < 9; ++i) {
        int ky = i/3, kx = i%3;
        pp1[i] = (d+1 < D_) ? sfus[d+1][py+ky][px+kx] : 0.0f;
      }
      float acc = bias;
      #pragma unroll
      for (int i = 0; i < 9; ++i) acc += pm1[i]*kw[i];
      #pragma unroll
      for (int i = 0; i < 9; ++i) acc += p0[i]*kw[9+i];
      #pragma unroll
      for (int i = 0; i < 9; ++i) acc += pp1[i]*kw[18+i];
      scost[d][pid] = acc;
      #pragma unroll
      for (int i = 0; i < 9; ++i) { pm1[i] = p0[i]; p0[i] = pp1[i]; }
    }
  }
  __syncthreads();

  // phase D: softmax / argmax / outputs, one thread per pixel
  if (tid < 64) {
    int tx = tid & 15, ty = tid >> 4;
    int gx = gx0 + tx, gy = gy0 + ty;
    int gp = gy*W_ + gx;
    float vmax = scost[0][tid];
    int am = 0;
    #pragma unroll
    for (int d = 1; d < D_; ++d) {
      float c = scost[d][tid];
      if (c > vmax) { vmax = c; am = d; }
    }
    float sum = 0.0f;
    #pragma unroll
    for (int d = 0; d < D_; ++d) sum += expf(scost[d][tid] - vmax);
    float inv = 1.0f / sum;
    #pragma unroll
    for (int d = 0; d < D_; ++d)
      out[(size_t)(2*HW) + (size_t)d*HW + gp] = expf(scost[d][tid] - vmax) * inv;
    out[gp] = dv[(size_t)am*HW + gp];
    out[HW + gp] = inv;
    // view_weights output
    int rint = (ty+1)*TXH + (tx+1);
    #pragma unroll
    for (int v = 0; v < NV; ++v)
      out[(size_t)(2*HW + D_*HW) + (size_t)v*HW + gp] = svw[v][rint];
  }
}

// ---------------- launch ----------------
extern "C" void kernel_launch(void* const* d_in, const int* in_sizes, int n_in,
                              void* d_out, int out_size, void* d_ws, size_t ws_size,
                              hipStream_t stream) {
  const float* feat = (const float*)d_in[0];
  const float* pm   = (const float*)d_in[1];
  const float* dv   = (const float*)d_in[2];
  const float* w0   = (const float*)d_in[3];
  const float* b0   = (const float*)d_in[4];
  const float* w1   = (const float*)d_in[5];
  const float* b1   = (const float*)d_in[6];
  const float* w2   = (const float*)d_in[7];
  const float* b2   = (const float*)d_in[8];
  const float* rw   = (const float*)d_in[9];
  const float* rb   = (const float*)d_in[10];
  float* out = (float*)d_out;
  float* ws  = (float*)d_ws;

  // workspace layout (floats)
  float* xf   = ws;                  // 48 (pad 64)
  float* tf   = ws + 64;             // 5*HW*C + 64 zero-pad = 3,276,864 floats
  float* sim  = ws + 3276928;        // 4*48*HW = 3,932,160
  float* yp   = ws + 7209088;        // 4*2*HW = 163,840
  // high-water mark: ~7.37M floats = ~28.1 MB

  hipLaunchKernelGGL(k_xform, dim3(1), dim3(64), 0, stream, pm, xf);
  hipMemsetAsync(tf + (size_t)5*HW*C_, 0, 64*sizeof(float), stream);
  hipLaunchKernelGGL(k_transpose, dim3(HW/64, 5), dim3(256), 0, stream, feat, tf);
  hipLaunchKernelGGL(k_warp, dim3((NV*HW*8)/256), dim3(256), 0, stream, tf, dv, xf, sim);
  hipLaunchKernelGGL(k_mlp, dim3((NV*NCH*HW)/256), dim3(256), 0, stream,
                     sim, w0, b0, w1, b1, w2, b2, yp);
  hipLaunchKernelGGL(k_fct, dim3(W_/TX, H_/TY), dim3(256), 0, stream,
                     sim, yp, rw, rb, dv, out);
}